// Round 1
// baseline (610.423 us; speedup 1.0000x reference)
//
#include <hip/hip_runtime.h>
#include <hip/hip_bf16.h>
#include <math.h>

#define GLOBAL_AS __attribute__((address_space(1)))
#define LDS_AS __attribute__((address_space(3)))

typedef __bf16 bf16x8 __attribute__((ext_vector_type(8)));
typedef float f32x4 __attribute__((ext_vector_type(4)));
typedef unsigned short u16x8 __attribute__((ext_vector_type(8)));
typedef unsigned short u16x4 __attribute__((ext_vector_type(4)));

static constexpr int BB = 4, SS = 2048, DD = 1024, HH = 16, DKK = 64;
static constexpr int MM = BB * SS;      // 8192 rows
static constexpr int NQKV = 3 * DD;     // 3072

__device__ inline unsigned short f2bf(float f) {
  union { float f; unsigned int u; } v; v.f = f;
  unsigned int r = v.u + 0x7fffu + ((v.u >> 16) & 1u);
  return (unsigned short)(r >> 16);
}

// ---------------- fp32 -> bf16 convert ----------------
__global__ __launch_bounds__(256) void cvt_kernel(const float* __restrict__ in,
                                                  unsigned short* __restrict__ out,
                                                  int n4) {
  int i = blockIdx.x * blockDim.x + threadIdx.x;
  if (i < n4) {
    float4 v = reinterpret_cast<const float4*>(in)[i];
    u16x4 o;
    o[0] = f2bf(v.x); o[1] = f2bf(v.y); o[2] = f2bf(v.z); o[3] = f2bf(v.w);
    *reinterpret_cast<u16x4*>(out + (size_t)i * 4) = o;
  }
}

// ---------------- NT GEMM: C[M,N] = A[M,K] * B[N,K]^T ----------------
// 128x128 tile, BK=64, 4 waves (2x2), 16x16x32 bf16 MFMA, global_load_lds staging.
template <int OUT_BF16>
__global__ __launch_bounds__(256) void gemm_nt(const unsigned short* __restrict__ A,
                                               const unsigned short* __restrict__ Bm,
                                               void* __restrict__ Cout,
                                               const float* __restrict__ bias,
                                               int Ndim, int K) {
  __shared__ __align__(16) unsigned short Asm[128 * 64];
  __shared__ __align__(16) unsigned short Bsm[128 * 64];
  const int tid = threadIdx.x, wv = tid >> 6, ln = tid & 63;
  const int bm0 = blockIdx.y * 128, bn0 = blockIdx.x * 128;
  const int wr = (wv >> 1) * 64, wc = (wv & 1) * 64;
  const int cl = ln & 15;        // A-row / B-col within 16
  const int ck = ln >> 4;        // k-chunk selector
  f32x4 acc[4][4] = {};

  for (int k0 = 0; k0 < K; k0 += 64) {
#pragma unroll
    for (int i = 0; i < 4; ++i) {
      int row = wv * 32 + i * 8 + (ln >> 3);
      int ch = (ln & 7) * 8;
      const unsigned short* ga = A + (size_t)(bm0 + row) * K + k0 + ch;
      const unsigned short* gb = Bm + (size_t)(bn0 + row) * K + k0 + ch;
      __builtin_amdgcn_global_load_lds((GLOBAL_AS void*)ga, (LDS_AS void*)(Asm + wv * 2048 + i * 512), 16, 0, 0);
      __builtin_amdgcn_global_load_lds((GLOBAL_AS void*)gb, (LDS_AS void*)(Bsm + wv * 2048 + i * 512), 16, 0, 0);
    }
    __syncthreads();
#pragma unroll
    for (int kk = 0; kk < 2; ++kk) {
      bf16x8 af[4], bfr[4];
#pragma unroll
      for (int m = 0; m < 4; ++m)
        af[m] = *reinterpret_cast<const bf16x8*>(Asm + (wr + m * 16 + cl) * 64 + kk * 32 + ck * 8);
#pragma unroll
      for (int n = 0; n < 4; ++n)
        bfr[n] = *reinterpret_cast<const bf16x8*>(Bsm + (wc + n * 16 + cl) * 64 + kk * 32 + ck * 8);
#pragma unroll
      for (int m = 0; m < 4; ++m)
#pragma unroll
        for (int n = 0; n < 4; ++n)
          acc[m][n] = __builtin_amdgcn_mfma_f32_16x16x32_bf16(af[m], bfr[n], acc[m][n], 0, 0, 0);
    }
    __syncthreads();
  }
  const int crow0 = ck * 4;
#pragma unroll
  for (int m = 0; m < 4; ++m) {
#pragma unroll
    for (int n = 0; n < 4; ++n) {
      int col = bn0 + wc + n * 16 + cl;
#pragma unroll
      for (int r = 0; r < 4; ++r) {
        int row = bm0 + wr + m * 16 + crow0 + r;
        float v = acc[m][n][r];
        if constexpr (OUT_BF16) {
          ((unsigned short*)Cout)[(size_t)row * Ndim + col] = f2bf(v);
        } else {
          ((float*)Cout)[(size_t)row * Ndim + col] = v + bias[col];
        }
      }
    }
  }
}

// ---------------- V transpose: qkv V-part -> Vt[b,h,dk,s] ----------------
__global__ __launch_bounds__(256) void vt_kernel(const unsigned short* __restrict__ qkv,
                                                 unsigned short* __restrict__ vt) {
  const int st = blockIdx.x, h = blockIdx.y, b = blockIdx.z;
  const int s0 = st * 64;
  __shared__ __align__(16) unsigned short tile[64][72];
  const int t = threadIdx.x;
  const int rs = t >> 2;            // 0..63
  const int c4 = (t & 3) * 16;      // 0,16,32,48
#pragma unroll
  for (int j2 = 0; j2 < 2; ++j2) {
    u16x8 v = *reinterpret_cast<const u16x8*>(qkv + (size_t)(b * SS + s0 + rs) * NQKV + 2 * DD + h * DKK + c4 + j2 * 8);
#pragma unroll
    for (int j = 0; j < 8; ++j) tile[rs][c4 + j2 * 8 + j] = v[j];
  }
  __syncthreads();
#pragma unroll
  for (int j2 = 0; j2 < 2; ++j2) {
    u16x8 v;
#pragma unroll
    for (int j = 0; j < 8; ++j) v[j] = tile[c4 + j2 * 8 + j][rs];
    *reinterpret_cast<u16x8*>(vt + ((size_t)((b * HH + h) * 64 + rs)) * SS + s0 + c4 + j2 * 8) = v;
  }
}

// ---------------- causal flash attention ----------------
// grid (S/64, H, B); 4 waves, each owns 16 q-rows. KV tiles of 64.
__global__ __launch_bounds__(256) void attn_kernel(const unsigned short* __restrict__ qkv,
                                                   const unsigned short* __restrict__ vt,
                                                   unsigned short* __restrict__ attn_out) {
  const int qt = blockIdx.x, h = blockIdx.y, b = blockIdx.z;
  const int tid = threadIdx.x, wv = tid >> 6, ln = tid & 63;
  const int q0 = qt * 64;
  const int cl = ln & 15, ck = ln >> 4;
  const int crow0 = ck * 4;
  __shared__ __align__(16) unsigned short P_lds[4][16][72];

  // preload Q fragments (A-operand rows = q0 + wv*16 + cl)
  const int qrow = q0 + wv * 16 + cl;
  bf16x8 qf[2];
#pragma unroll
  for (int kk = 0; kk < 2; ++kk)
    qf[kk] = *reinterpret_cast<const bf16x8*>(qkv + (size_t)(b * SS + qrow) * NQKV + h * DKK + kk * 32 + ck * 8);

  f32x4 o[4] = {};
  float mrow[4], lsum[4];
#pragma unroll
  for (int r = 0; r < 4; ++r) { mrow[r] = -INFINITY; lsum[r] = 0.f; }
  const int my_q = q0 + wv * 16 + crow0;

  const int ntiles = qt + 1;
  unsigned short* pw = &P_lds[wv][0][0];

  for (int t = 0; t < ntiles; ++t) {
    const int kv0 = t * 64;
    f32x4 sc[4];
#pragma unroll
    for (int cc = 0; cc < 4; ++cc) {
      f32x4 z = {};
      sc[cc] = z;
      const int kvr = kv0 + cc * 16 + cl;
#pragma unroll
      for (int kk = 0; kk < 2; ++kk) {
        bf16x8 kf = *reinterpret_cast<const bf16x8*>(qkv + (size_t)(b * SS + kvr) * NQKV + DD + h * DKK + kk * 32 + ck * 8);
        sc[cc] = __builtin_amdgcn_mfma_f32_16x16x32_bf16(qf[kk], kf, sc[cc], 0, 0, 0);
      }
    }
    // scale + causal mask + row max
    float tmax[4];
#pragma unroll
    for (int r = 0; r < 4; ++r) tmax[r] = -INFINITY;
#pragma unroll
    for (int cc = 0; cc < 4; ++cc) {
      const int col = kv0 + cc * 16 + cl;
#pragma unroll
      for (int r = 0; r < 4; ++r) {
        float s = sc[cc][r] * 0.125f;
        s = (col <= my_q + r) ? s : -INFINITY;
        sc[cc][r] = s;
        tmax[r] = fmaxf(tmax[r], s);
      }
    }
#pragma unroll
    for (int r = 0; r < 4; ++r) {
#pragma unroll
      for (int off = 1; off < 16; off <<= 1)
        tmax[r] = fmaxf(tmax[r], __shfl_xor(tmax[r], off));
    }
    float alpha[4];
#pragma unroll
    for (int r = 0; r < 4; ++r) {
      float mn = fmaxf(mrow[r], tmax[r]);
      alpha[r] = __expf(mrow[r] - mn);
      mrow[r] = mn;
    }
    float psum[4] = {0.f, 0.f, 0.f, 0.f};
#pragma unroll
    for (int cc = 0; cc < 4; ++cc) {
#pragma unroll
      for (int r = 0; r < 4; ++r) {
        float p = __expf(sc[cc][r] - mrow[r]);
        sc[cc][r] = p;
        psum[r] += p;
      }
    }
#pragma unroll
    for (int r = 0; r < 4; ++r) {
#pragma unroll
      for (int off = 1; off < 16; off <<= 1)
        psum[r] += __shfl_xor(psum[r], off);
      lsum[r] = lsum[r] * alpha[r] + psum[r];
    }
#pragma unroll
    for (int dc = 0; dc < 4; ++dc)
#pragma unroll
      for (int r = 0; r < 4; ++r)
        o[dc][r] *= alpha[r];

    __syncthreads();
#pragma unroll
    for (int cc = 0; cc < 4; ++cc)
#pragma unroll
      for (int r = 0; r < 4; ++r)
        pw[(crow0 + r) * 72 + cc * 16 + cl] = f2bf(sc[cc][r]);
    __syncthreads();

    // PV: A = P[16 x 64], B-op = V[kv][dk] via Vt rows
#pragma unroll
    for (int ks = 0; ks < 2; ++ks) {
      bf16x8 pf = *reinterpret_cast<const bf16x8*>(pw + cl * 72 + ks * 32 + ck * 8);
#pragma unroll
      for (int dc = 0; dc < 4; ++dc) {
        bf16x8 vf = *reinterpret_cast<const bf16x8*>(vt + ((size_t)((b * HH + h) * 64 + dc * 16 + cl)) * SS + kv0 + ks * 32 + ck * 8);
        o[dc] = __builtin_amdgcn_mfma_f32_16x16x32_bf16(pf, vf, o[dc], 0, 0, 0);
      }
    }
  }

  // epilogue: O / lsum -> attn_out[b, q, h*64+dk] (bf16)
#pragma unroll
  for (int r = 0; r < 4; ++r) {
    float inv = 1.0f / lsum[r];
    int q = my_q + r;
#pragma unroll
    for (int dc = 0; dc < 4; ++dc) {
      int dk = dc * 16 + cl;
      attn_out[(size_t)(b * SS + q) * DD + h * DKK + dk] = f2bf(o[dc][r] * inv);
    }
  }
}

// ---------------- launch ----------------
extern "C" void kernel_launch(void* const* d_in, const int* in_sizes, int n_in,
                              void* d_out, int out_size, void* d_ws, size_t ws_size,
                              hipStream_t stream) {
  const float* x = (const float*)d_in[0];
  const float* w_q = (const float*)d_in[1];
  const float* w_k = (const float*)d_in[2];
  const float* w_v = (const float*)d_in[3];
  const float* w_o = (const float*)d_in[4];
  const float* b_o = (const float*)d_in[5];
  float* out = (float*)d_out;

  unsigned short* ws = (unsigned short*)d_ws;
  unsigned short* x_bf = ws;                               // 8192*1024
  unsigned short* w_qkv = x_bf + (size_t)MM * DD;          // 3072*1024
  unsigned short* w_obf = w_qkv + (size_t)NQKV * DD;       // 1024*1024
  unsigned short* qkv = w_obf + (size_t)DD * DD;           // 8192*3072
  unsigned short* vt = qkv + (size_t)MM * NQKV;            // B*H*DK*S = 8388608
  unsigned short* attn = vt + (size_t)BB * HH * DKK * SS;  // 8192*1024

  // converts
  cvt_kernel<<<(MM * DD / 4 + 255) / 256, 256, 0, stream>>>(x, x_bf, MM * DD / 4);
  cvt_kernel<<<(DD * DD / 4 + 255) / 256, 256, 0, stream>>>(w_q, w_qkv, DD * DD / 4);
  cvt_kernel<<<(DD * DD / 4 + 255) / 256, 256, 0, stream>>>(w_k, w_qkv + (size_t)DD * DD, DD * DD / 4);
  cvt_kernel<<<(DD * DD / 4 + 255) / 256, 256, 0, stream>>>(w_v, w_qkv + (size_t)2 * DD * DD, DD * DD / 4);
  cvt_kernel<<<(DD * DD / 4 + 255) / 256, 256, 0, stream>>>(w_o, w_obf, DD * DD / 4);

  // QKV projection: [8192,3072] = x_bf @ w_qkv^T
  gemm_nt<1><<<dim3(NQKV / 128, MM / 128), 256, 0, stream>>>(x_bf, w_qkv, qkv, nullptr, NQKV, DD);

  // V transpose
  vt_kernel<<<dim3(SS / 64, HH, BB), 256, 0, stream>>>(qkv, vt);

  // attention
  attn_kernel<<<dim3(SS / 64, HH, BB), 256, 0, stream>>>(qkv, vt, attn);

  // output projection: [8192,1024] = attn @ w_o^T + b_o
  gemm_nt<0><<<dim3(DD / 128, MM / 128), 256, 0, stream>>>(attn, w_obf, out, b_o, DD, DD);
}

// Round 2
// 354.868 us; speedup vs baseline: 1.7201x; 1.7201x over previous
//
#include <hip/hip_runtime.h>
#include <hip/hip_bf16.h>
#include <math.h>

#define GLOBAL_AS __attribute__((address_space(1)))
#define LDS_AS __attribute__((address_space(3)))

typedef __bf16 bf16x8 __attribute__((ext_vector_type(8)));
typedef float f32x4 __attribute__((ext_vector_type(4)));
typedef unsigned short u16x8 __attribute__((ext_vector_type(8)));
typedef unsigned short u16x4 __attribute__((ext_vector_type(4)));

static constexpr int BB = 4, SS = 2048, DD = 1024, HH = 16, DKK = 64;
static constexpr int MM = BB * SS;      // 8192 rows
static constexpr int NQKV = 3 * DD;     // 3072

__device__ inline unsigned short f2bf(float f) {
  union { float f; unsigned int u; } v; v.f = f;
  unsigned int r = v.u + 0x7fffu + ((v.u >> 16) & 1u);
  return (unsigned short)(r >> 16);
}

// ---------------- fp32 -> bf16 convert ----------------
__global__ __launch_bounds__(256) void cvt_kernel(const float* __restrict__ in,
                                                  unsigned short* __restrict__ out,
                                                  int n4) {
  int i = blockIdx.x * blockDim.x + threadIdx.x;
  if (i < n4) {
    float4 v = reinterpret_cast<const float4*>(in)[i];
    u16x4 o;
    o[0] = f2bf(v.x); o[1] = f2bf(v.y); o[2] = f2bf(v.z); o[3] = f2bf(v.w);
    *reinterpret_cast<u16x4*>(out + (size_t)i * 4) = o;
  }
}

// ---------------- NT GEMM: C[M,N] = A[M,K] * B[N,K]^T ----------------
// MODE 0: f32 out + bias. MODE 1: bf16 out. MODE 2: bf16 out, cols<DD scaled by 0.125 (Q prescale).
template <int MODE>
__global__ __launch_bounds__(256) void gemm_nt(const unsigned short* __restrict__ A,
                                               const unsigned short* __restrict__ Bm,
                                               void* __restrict__ Cout,
                                               const float* __restrict__ bias,
                                               int Ndim, int K) {
  __shared__ __align__(16) unsigned short Asm[128 * 64];
  __shared__ __align__(16) unsigned short Bsm[128 * 64];
  const int tid = threadIdx.x, wv = tid >> 6, ln = tid & 63;
  const int bm0 = blockIdx.y * 128, bn0 = blockIdx.x * 128;
  const int wr = (wv >> 1) * 64, wc = (wv & 1) * 64;
  const int cl = ln & 15;        // A-row / B-col within 16
  const int ck = ln >> 4;        // k-chunk selector
  f32x4 acc[4][4] = {};

  for (int k0 = 0; k0 < K; k0 += 64) {
#pragma unroll
    for (int i = 0; i < 4; ++i) {
      int row = wv * 32 + i * 8 + (ln >> 3);
      int ch = (ln & 7) * 8;
      const unsigned short* ga = A + (size_t)(bm0 + row) * K + k0 + ch;
      const unsigned short* gb = Bm + (size_t)(bn0 + row) * K + k0 + ch;
      __builtin_amdgcn_global_load_lds((GLOBAL_AS void*)ga, (LDS_AS void*)(Asm + wv * 2048 + i * 512), 16, 0, 0);
      __builtin_amdgcn_global_load_lds((GLOBAL_AS void*)gb, (LDS_AS void*)(Bsm + wv * 2048 + i * 512), 16, 0, 0);
    }
    __syncthreads();
#pragma unroll
    for (int kk = 0; kk < 2; ++kk) {
      bf16x8 af[4], bfr[4];
#pragma unroll
      for (int m = 0; m < 4; ++m)
        af[m] = *reinterpret_cast<const bf16x8*>(Asm + (wr + m * 16 + cl) * 64 + kk * 32 + ck * 8);
#pragma unroll
      for (int n = 0; n < 4; ++n)
        bfr[n] = *reinterpret_cast<const bf16x8*>(Bsm + (wc + n * 16 + cl) * 64 + kk * 32 + ck * 8);
#pragma unroll
      for (int m = 0; m < 4; ++m)
#pragma unroll
        for (int n = 0; n < 4; ++n)
          acc[m][n] = __builtin_amdgcn_mfma_f32_16x16x32_bf16(af[m], bfr[n], acc[m][n], 0, 0, 0);
    }
    __syncthreads();
  }
  const int crow0 = ck * 4;
#pragma unroll
  for (int m = 0; m < 4; ++m) {
#pragma unroll
    for (int n = 0; n < 4; ++n) {
      int col = bn0 + wc + n * 16 + cl;
#pragma unroll
      for (int r = 0; r < 4; ++r) {
        int row = bm0 + wr + m * 16 + crow0 + r;
        float v = acc[m][n][r];
        if constexpr (MODE == 0) {
          ((float*)Cout)[(size_t)row * Ndim + col] = v + bias[col];
        } else {
          if constexpr (MODE == 2) { if (col < DD) v *= 0.125f; }
          ((unsigned short*)Cout)[(size_t)row * Ndim + col] = f2bf(v);
        }
      }
    }
  }
}

// ---------------- V transpose: qkv V-part -> Vt[b,h,dk,s] ----------------
__global__ __launch_bounds__(256) void vt_kernel(const unsigned short* __restrict__ qkv,
                                                 unsigned short* __restrict__ vt) {
  const int st = blockIdx.x, h = blockIdx.y, b = blockIdx.z;
  const int s0 = st * 64;
  __shared__ __align__(16) unsigned short tile[64][72];
  const int t = threadIdx.x;
  const int rs = t >> 2;            // 0..63
  const int c4 = (t & 3) * 16;      // 0,16,32,48
#pragma unroll
  for (int j2 = 0; j2 < 2; ++j2) {
    u16x8 v = *reinterpret_cast<const u16x8*>(qkv + (size_t)(b * SS + s0 + rs) * NQKV + 2 * DD + h * DKK + c4 + j2 * 8);
#pragma unroll
    for (int j = 0; j < 8; ++j) tile[rs][c4 + j2 * 8 + j] = v[j];
  }
  __syncthreads();
#pragma unroll
  for (int j2 = 0; j2 < 2; ++j2) {
    u16x8 v;
#pragma unroll
    for (int j = 0; j < 8; ++j) v[j] = tile[c4 + j2 * 8 + j][rs];
    *reinterpret_cast<u16x8*>(vt + ((size_t)((b * HH + h) * 64 + rs)) * SS + s0 + c4 + j2 * 8) = v;
  }
}

// ---------------- causal flash attention ----------------
// grid (S/128, H, B); 4 waves, each owns 32 q-rows (2 m-fragments).
// K and Vt tiles (64x64 bf16) staged in LDS via global_load_lds, double-buffered,
// XOR chunk-swizzle (pre-swizzled global source + swizzled ds_read).
__global__ __launch_bounds__(256) void attn_kernel(const unsigned short* __restrict__ qkv,
                                                   const unsigned short* __restrict__ vt,
                                                   unsigned short* __restrict__ attn_out) {
  const int qt = blockIdx.x, h = blockIdx.y, b = blockIdx.z;
  const int tid = threadIdx.x, wv = tid >> 6, ln = tid & 63;
  const int q0 = qt * 128;
  const int cl = ln & 15, ck = ln >> 4;
  const int crow0 = ck * 4;
  const int bh = b * HH + h;

  __shared__ __align__(16) unsigned short Ks[2][64 * 64];
  __shared__ __align__(16) unsigned short Vs[2][64 * 64];
  __shared__ __align__(16) unsigned short Pl[4][32 * 72];

  const int qminw = q0 + wv * 32;
  const int qmaxw = qminw + 31;

  // Q fragments in registers (already prescaled by 0.125 in the QKV GEMM)
  bf16x8 qf[2][2];
#pragma unroll
  for (int m = 0; m < 2; ++m)
#pragma unroll
    for (int kk = 0; kk < 2; ++kk)
      qf[m][kk] = *reinterpret_cast<const bf16x8*>(
          qkv + (size_t)(b * SS + qminw + m * 16 + cl) * NQKV + h * DKK + kk * 32 + ck * 8);

  f32x4 o[2][4] = {};
  float mrow[2][4], lsum[2][4];
#pragma unroll
  for (int m = 0; m < 2; ++m)
#pragma unroll
    for (int r = 0; r < 4; ++r) { mrow[m][r] = -INFINITY; lsum[m][r] = 0.f; }

  unsigned short* pw = &Pl[wv][0];

  auto stage = [&](int bsel, int kv0s) {
#pragma unroll
    for (int i = 0; i < 2; ++i) {
      int idx = wv * 2 + i;
      int row = idx * 8 + (ln >> 3);
      int sch = (ln & 7) ^ (row & 7);   // pre-swizzled source chunk
      const unsigned short* gk = qkv + ((size_t)(b * SS + kv0s + row) * NQKV + DD + h * DKK + sch * 8);
      __builtin_amdgcn_global_load_lds((GLOBAL_AS void*)gk, (LDS_AS void*)(&Ks[bsel][idx * 512]), 16, 0, 0);
      const unsigned short* gv = vt + ((size_t)(bh * 64 + row) * SS + kv0s + sch * 8);
      __builtin_amdgcn_global_load_lds((GLOBAL_AS void*)gv, (LDS_AS void*)(&Vs[bsel][idx * 512]), 16, 0, 0);
    }
  };

  const int nt = 2 * qt + 2;
  stage(0, 0);
  __syncthreads();
  int buf = 0;

  for (int t = 0; t < nt; ++t) {
    const int kv0 = t * 64;
    if (t + 1 < nt) stage(buf ^ 1, (t + 1) * 64);

    if (kv0 <= qmaxw) {  // wave-uniform: skip fully-masked tiles
      const unsigned short* kb = &Ks[buf][0];
      const unsigned short* vb = &Vs[buf][0];

      // ---- QK^T ----
      f32x4 sc[2][4];
#pragma unroll
      for (int cc = 0; cc < 4; ++cc) {
        const int kvr = cc * 16 + cl;
        bf16x8 kf0 = *reinterpret_cast<const bf16x8*>(kb + kvr * 64 + ((ck ^ (kvr & 7)) * 8));
        bf16x8 kf1 = *reinterpret_cast<const bf16x8*>(kb + kvr * 64 + (((4 + ck) ^ (kvr & 7)) * 8));
#pragma unroll
        for (int m = 0; m < 2; ++m) {
          f32x4 z = {};
          z = __builtin_amdgcn_mfma_f32_16x16x32_bf16(qf[m][0], kf0, z, 0, 0, 0);
          z = __builtin_amdgcn_mfma_f32_16x16x32_bf16(qf[m][1], kf1, z, 0, 0, 0);
          sc[m][cc] = z;
        }
      }

      // ---- causal mask (only near the diagonal) ----
      if (kv0 + 63 > qminw) {
#pragma unroll
        for (int cc = 0; cc < 4; ++cc) {
          const int col = kv0 + cc * 16 + cl;
#pragma unroll
          for (int m = 0; m < 2; ++m) {
            const int qr = qminw + m * 16 + crow0;
#pragma unroll
            for (int r = 0; r < 4; ++r)
              sc[m][cc][r] = (col <= qr + r) ? sc[m][cc][r] : -INFINITY;
          }
        }
      }

      // ---- online softmax ----
#pragma unroll
      for (int m = 0; m < 2; ++m) {
#pragma unroll
        for (int r = 0; r < 4; ++r) {
          float tm = fmaxf(fmaxf(sc[m][0][r], sc[m][1][r]), fmaxf(sc[m][2][r], sc[m][3][r]));
#pragma unroll
          for (int off = 1; off < 16; off <<= 1) tm = fmaxf(tm, __shfl_xor(tm, off));
          float mn = fmaxf(mrow[m][r], tm);
          float al = __expf(mrow[m][r] - mn);
          mrow[m][r] = mn;
          float ps = 0.f;
#pragma unroll
          for (int cc = 0; cc < 4; ++cc) {
            float p = __expf(sc[m][cc][r] - mn);
            sc[m][cc][r] = p;
            ps += p;
          }
#pragma unroll
          for (int off = 1; off < 16; off <<= 1) ps += __shfl_xor(ps, off);
          lsum[m][r] = lsum[m][r] * al + ps;
#pragma unroll
          for (int dc = 0; dc < 4; ++dc) o[m][dc][r] *= al;
        }
      }

      // ---- P -> LDS (bf16) ----
#pragma unroll
      for (int m = 0; m < 2; ++m)
#pragma unroll
        for (int cc = 0; cc < 4; ++cc)
#pragma unroll
          for (int r = 0; r < 4; ++r)
            pw[(m * 16 + crow0 + r) * 72 + cc * 16 + cl] = f2bf(sc[m][cc][r]);

      // ---- PV ----
#pragma unroll
      for (int ks = 0; ks < 2; ++ks) {
        bf16x8 pf[2];
#pragma unroll
        for (int m = 0; m < 2; ++m)
          pf[m] = *reinterpret_cast<const bf16x8*>(pw + (m * 16 + cl) * 72 + ks * 32 + ck * 8);
#pragma unroll
        for (int dc = 0; dc < 4; ++dc) {
          const int vr = dc * 16 + cl;
          bf16x8 vf = *reinterpret_cast<const bf16x8*>(vb + vr * 64 + (((ks * 4 + ck) ^ (vr & 7)) * 8));
#pragma unroll
          for (int m = 0; m < 2; ++m)
            o[m][dc] = __builtin_amdgcn_mfma_f32_16x16x32_bf16(pf[m], vf, o[m][dc], 0, 0, 0);
        }
      }
    }

    __syncthreads();
    buf ^= 1;
  }

  // ---- epilogue ----
#pragma unroll
  for (int m = 0; m < 2; ++m) {
#pragma unroll
    for (int r = 0; r < 4; ++r) {
      float inv = 1.0f / lsum[m][r];
      int q = qminw + m * 16 + crow0 + r;
#pragma unroll
      for (int dc = 0; dc < 4; ++dc)
        attn_out[(size_t)(b * SS + q) * DD + h * DKK + dc * 16 + cl] = f2bf(o[m][dc][r] * inv);
    }
  }
}

// ---------------- launch ----------------
extern "C" void kernel_launch(void* const* d_in, const int* in_sizes, int n_in,
                              void* d_out, int out_size, void* d_ws, size_t ws_size,
                              hipStream_t stream) {
  const float* x = (const float*)d_in[0];
  const float* w_q = (const float*)d_in[1];
  const float* w_k = (const float*)d_in[2];
  const float* w_v = (const float*)d_in[3];
  const float* w_o = (const float*)d_in[4];
  const float* b_o = (const float*)d_in[5];
  float* out = (float*)d_out;

  unsigned short* ws = (unsigned short*)d_ws;
  unsigned short* x_bf = ws;                               // 8192*1024
  unsigned short* w_qkv = x_bf + (size_t)MM * DD;          // 3072*1024
  unsigned short* w_obf = w_qkv + (size_t)NQKV * DD;       // 1024*1024
  unsigned short* qkv = w_obf + (size_t)DD * DD;           // 8192*3072
  unsigned short* vt = qkv + (size_t)MM * NQKV;            // B*H*DK*S = 8388608
  unsigned short* attn = vt + (size_t)BB * HH * DKK * SS;  // 8192*1024

  // converts
  cvt_kernel<<<(MM * DD / 4 + 255) / 256, 256, 0, stream>>>(x, x_bf, MM * DD / 4);
  cvt_kernel<<<(DD * DD / 4 + 255) / 256, 256, 0, stream>>>(w_q, w_qkv, DD * DD / 4);
  cvt_kernel<<<(DD * DD / 4 + 255) / 256, 256, 0, stream>>>(w_k, w_qkv + (size_t)DD * DD, DD * DD / 4);
  cvt_kernel<<<(DD * DD / 4 + 255) / 256, 256, 0, stream>>>(w_v, w_qkv + (size_t)2 * DD * DD, DD * DD / 4);
  cvt_kernel<<<(DD * DD / 4 + 255) / 256, 256, 0, stream>>>(w_o, w_obf, DD * DD / 4);

  // QKV projection: [8192,3072] = x_bf @ w_qkv^T (Q cols prescaled by 0.125)
  gemm_nt<2><<<dim3(NQKV / 128, MM / 128), 256, 0, stream>>>(x_bf, w_qkv, qkv, nullptr, NQKV, DD);

  // V transpose
  vt_kernel<<<dim3(SS / 64, HH, BB), 256, 0, stream>>>(qkv, vt);

  // attention
  attn_kernel<<<dim3(SS / 128, HH, BB), 256, 0, stream>>>(qkv, vt, attn);

  // output projection: [8192,1024] = attn @ w_o^T + b_o
  gemm_nt<0><<<dim3(DD / 128, MM / 128), 256, 0, stream>>>(attn, w_obf, out, b_o, DD, DD);
}

// Round 3
// 250.894 us; speedup vs baseline: 2.4330x; 1.4144x over previous
//
#include <hip/hip_runtime.h>
#include <hip/hip_bf16.h>
#include <math.h>

#define GLOBAL_AS __attribute__((address_space(1)))
#define LDS_AS __attribute__((address_space(3)))

typedef __bf16 bf16x8 __attribute__((ext_vector_type(8)));
typedef float f32x4 __attribute__((ext_vector_type(4)));
typedef unsigned short u16x8 __attribute__((ext_vector_type(8)));
typedef unsigned short u16x4 __attribute__((ext_vector_type(4)));

static constexpr int BB = 4, SS = 2048, DD = 1024, HH = 16, DKK = 64;
static constexpr int MM = BB * SS;      // 8192 rows
static constexpr int NQKV = 3 * DD;     // 3072
static constexpr int NQT = SS / 128;    // 16 q-tiles

__device__ inline unsigned short f2bf(float f) {
  union { float f; unsigned int u; } v; v.f = f;
  unsigned int r = v.u + 0x7fffu + ((v.u >> 16) & 1u);
  return (unsigned short)(r >> 16);
}

// ---------------- fp32 -> bf16 convert ----------------
__global__ __launch_bounds__(256) void cvt_kernel(const float* __restrict__ in,
                                                  unsigned short* __restrict__ out,
                                                  int n4) {
  int i = blockIdx.x * blockDim.x + threadIdx.x;
  if (i < n4) {
    float4 v = reinterpret_cast<const float4*>(in)[i];
    u16x4 o;
    o[0] = f2bf(v.x); o[1] = f2bf(v.y); o[2] = f2bf(v.z); o[3] = f2bf(v.w);
    *reinterpret_cast<u16x4*>(out + (size_t)i * 4) = o;
  }
}

// ---------------- NT GEMM: C[M,N] = A[M,K] * B[N,K]^T ----------------
// MODE 0: f32 out + bias. MODE 1: bf16 out. MODE 2: bf16 out, cols<DD scaled by 0.125*log2(e).
template <int MODE>
__global__ __launch_bounds__(256) void gemm_nt(const unsigned short* __restrict__ A,
                                               const unsigned short* __restrict__ Bm,
                                               void* __restrict__ Cout,
                                               const float* __restrict__ bias,
                                               int Ndim, int K) {
  __shared__ __align__(16) unsigned short Asm[128 * 64];
  __shared__ __align__(16) unsigned short Bsm[128 * 64];
  const int tid = threadIdx.x, wv = tid >> 6, ln = tid & 63;
  const int bm0 = blockIdx.y * 128, bn0 = blockIdx.x * 128;
  const int wr = (wv >> 1) * 64, wc = (wv & 1) * 64;
  const int cl = ln & 15;        // A-row / B-col within 16
  const int ck = ln >> 4;        // k-chunk selector
  f32x4 acc[4][4] = {};

  for (int k0 = 0; k0 < K; k0 += 64) {
#pragma unroll
    for (int i = 0; i < 4; ++i) {
      int row = wv * 32 + i * 8 + (ln >> 3);
      int ch = (ln & 7) * 8;
      const unsigned short* ga = A + (size_t)(bm0 + row) * K + k0 + ch;
      const unsigned short* gb = Bm + (size_t)(bn0 + row) * K + k0 + ch;
      __builtin_amdgcn_global_load_lds((GLOBAL_AS void*)ga, (LDS_AS void*)(Asm + wv * 2048 + i * 512), 16, 0, 0);
      __builtin_amdgcn_global_load_lds((GLOBAL_AS void*)gb, (LDS_AS void*)(Bsm + wv * 2048 + i * 512), 16, 0, 0);
    }
    __syncthreads();
#pragma unroll
    for (int kk = 0; kk < 2; ++kk) {
      bf16x8 af[4], bfr[4];
#pragma unroll
      for (int m = 0; m < 4; ++m)
        af[m] = *reinterpret_cast<const bf16x8*>(Asm + (wr + m * 16 + cl) * 64 + kk * 32 + ck * 8);
#pragma unroll
      for (int n = 0; n < 4; ++n)
        bfr[n] = *reinterpret_cast<const bf16x8*>(Bsm + (wc + n * 16 + cl) * 64 + kk * 32 + ck * 8);
#pragma unroll
      for (int m = 0; m < 4; ++m)
#pragma unroll
        for (int n = 0; n < 4; ++n)
          acc[m][n] = __builtin_amdgcn_mfma_f32_16x16x32_bf16(af[m], bfr[n], acc[m][n], 0, 0, 0);
    }
    __syncthreads();
  }
  const int crow0 = ck * 4;
#pragma unroll
  for (int m = 0; m < 4; ++m) {
#pragma unroll
    for (int n = 0; n < 4; ++n) {
      int col = bn0 + wc + n * 16 + cl;
#pragma unroll
      for (int r = 0; r < 4; ++r) {
        int row = bm0 + wr + m * 16 + crow0 + r;
        float v = acc[m][n][r];
        if constexpr (MODE == 0) {
          ((float*)Cout)[(size_t)row * Ndim + col] = v + bias[col];
        } else {
          if constexpr (MODE == 2) { if (col < DD) v *= 0.18033688011112042f; } // 0.125*log2(e)
          ((unsigned short*)Cout)[(size_t)row * Ndim + col] = f2bf(v);
        }
      }
    }
  }
}

// ---------------- V transpose: qkv V-part -> Vt[b,h,dk,s] ----------------
__global__ __launch_bounds__(256) void vt_kernel(const unsigned short* __restrict__ qkv,
                                                 unsigned short* __restrict__ vt) {
  const int st = blockIdx.x, h = blockIdx.y, b = blockIdx.z;
  const int s0 = st * 64;
  __shared__ __align__(16) unsigned short tile[64][72];
  const int t = threadIdx.x;
  const int rs = t >> 2;            // 0..63
  const int c4 = (t & 3) * 16;      // 0,16,32,48
#pragma unroll
  for (int j2 = 0; j2 < 2; ++j2) {
    u16x8 v = *reinterpret_cast<const u16x8*>(qkv + (size_t)(b * SS + s0 + rs) * NQKV + 2 * DD + h * DKK + c4 + j2 * 8);
#pragma unroll
    for (int j = 0; j < 8; ++j) tile[rs][c4 + j2 * 8 + j] = v[j];
  }
  __syncthreads();
#pragma unroll
  for (int j2 = 0; j2 < 2; ++j2) {
    u16x8 v;
#pragma unroll
    for (int j = 0; j < 8; ++j) v[j] = tile[c4 + j2 * 8 + j][rs];
    *reinterpret_cast<u16x8*>(vt + ((size_t)((b * HH + h) * 64 + rs)) * SS + s0 + c4 + j2 * 8) = v;
  }
}

// ---------------- causal flash attention ----------------
// grid (NQT/2, H, B); block i does q-tiles (NQT-1-i) then (i)  -> balanced 34 tile-units.
// 4 waves, each owns 32 q-rows. K/Vt tiles (64x64) double-buffered in LDS, XOR chunk-swizzle.
// Q prescaled by 0.125*log2(e); softmax in exp2 space; defer-rescale THR=8.
__global__ __launch_bounds__(256) void attn_kernel(const unsigned short* __restrict__ qkv,
                                                   const unsigned short* __restrict__ vt,
                                                   unsigned short* __restrict__ attn_out) {
  const int pi = blockIdx.x, h = blockIdx.y, b = blockIdx.z;
  const int tid = threadIdx.x, wv = tid >> 6, ln = tid & 63;
  const int cl = ln & 15, ck = ln >> 4;
  const int crow0 = ck * 4;
  const int bh = b * HH + h;

  __shared__ __align__(16) unsigned short Ks[2][64 * 64];
  __shared__ __align__(16) unsigned short Vs[2][64 * 64];
  __shared__ __align__(16) unsigned short Pl[4][32 * 72];
  unsigned short* pw = &Pl[wv][0];

  auto stage = [&](int bsel, int kv0s) {
#pragma unroll
    for (int i = 0; i < 2; ++i) {
      int idx = wv * 2 + i;
      int row = idx * 8 + (ln >> 3);
      int sch = (ln & 7) ^ (row & 7);   // pre-swizzled source chunk
      const unsigned short* gk = qkv + ((size_t)(b * SS + kv0s + row) * NQKV + DD + h * DKK + sch * 8);
      __builtin_amdgcn_global_load_lds((GLOBAL_AS void*)gk, (LDS_AS void*)(&Ks[bsel][idx * 512]), 16, 0, 0);
      const unsigned short* gv = vt + ((size_t)(bh * 64 + row) * SS + kv0s + sch * 8);
      __builtin_amdgcn_global_load_lds((GLOBAL_AS void*)gv, (LDS_AS void*)(&Vs[bsel][idx * 512]), 16, 0, 0);
    }
  };

  auto process = [&](int qt) {
    const int q0 = qt * 128;
    const int qminw = q0 + wv * 32;
    const int qmaxw = qminw + 31;

    bf16x8 qf[2][2];
#pragma unroll
    for (int m = 0; m < 2; ++m)
#pragma unroll
      for (int kk = 0; kk < 2; ++kk)
        qf[m][kk] = *reinterpret_cast<const bf16x8*>(
            qkv + (size_t)(b * SS + qminw + m * 16 + cl) * NQKV + h * DKK + kk * 32 + ck * 8);

    f32x4 o[2][4] = {};
    float mrow[2][4], lsum[2][4];
#pragma unroll
    for (int m = 0; m < 2; ++m)
#pragma unroll
      for (int r = 0; r < 4; ++r) { mrow[m][r] = -INFINITY; lsum[m][r] = 0.f; }

    const int nt = 2 * qt + 2;
    stage(0, 0);
    __syncthreads();
    int buf = 0;

    for (int t = 0; t < nt; ++t) {
      const int kv0 = t * 64;
      if (t + 1 < nt) stage(buf ^ 1, (t + 1) * 64);

      if (kv0 <= qmaxw) {
        const unsigned short* kb = &Ks[buf][0];
        const unsigned short* vb = &Vs[buf][0];

        // ---- QK^T (logits already in log2 space) ----
        f32x4 sc[2][4];
#pragma unroll
        for (int cc = 0; cc < 4; ++cc) {
          const int kvr = cc * 16 + cl;
          bf16x8 kf0 = *reinterpret_cast<const bf16x8*>(kb + kvr * 64 + ((ck ^ (kvr & 7)) * 8));
          bf16x8 kf1 = *reinterpret_cast<const bf16x8*>(kb + kvr * 64 + (((4 + ck) ^ (kvr & 7)) * 8));
#pragma unroll
          for (int m = 0; m < 2; ++m) {
            f32x4 z = {};
            z = __builtin_amdgcn_mfma_f32_16x16x32_bf16(qf[m][0], kf0, z, 0, 0, 0);
            z = __builtin_amdgcn_mfma_f32_16x16x32_bf16(qf[m][1], kf1, z, 0, 0, 0);
            sc[m][cc] = z;
          }
        }

        // ---- causal mask (only near the diagonal) ----
        if (kv0 + 63 > qminw) {
#pragma unroll
          for (int cc = 0; cc < 4; ++cc) {
            const int col = kv0 + cc * 16 + cl;
#pragma unroll
            for (int m = 0; m < 2; ++m) {
              const int qr = qminw + m * 16 + crow0;
#pragma unroll
              for (int r = 0; r < 4; ++r)
                sc[m][cc][r] = (col <= qr + r) ? sc[m][cc][r] : -INFINITY;
            }
          }
        }

        // ---- row max + defer-rescale decision ----
        float tm[2][4];
        float growth = -INFINITY;
#pragma unroll
        for (int m = 0; m < 2; ++m)
#pragma unroll
          for (int r = 0; r < 4; ++r) {
            float t0 = fmaxf(fmaxf(sc[m][0][r], sc[m][1][r]), fmaxf(sc[m][2][r], sc[m][3][r]));
#pragma unroll
            for (int off = 1; off < 16; off <<= 1) t0 = fmaxf(t0, __shfl_xor(t0, off));
            tm[m][r] = t0;
            growth = fmaxf(growth, t0 - mrow[m][r]);
          }
        if (__ballot(growth > 8.0f)) {  // rescale path (wave-uniform)
#pragma unroll
          for (int m = 0; m < 2; ++m)
#pragma unroll
            for (int r = 0; r < 4; ++r) {
              float mn = fmaxf(mrow[m][r], tm[m][r]);
              float al = __builtin_amdgcn_exp2f(mrow[m][r] - mn);
              mrow[m][r] = mn;
              lsum[m][r] *= al;
#pragma unroll
              for (int dc = 0; dc < 4; ++dc) o[m][dc][r] *= al;
            }
        }

        // ---- P = exp2(S - m), row sums ----
#pragma unroll
        for (int m = 0; m < 2; ++m)
#pragma unroll
          for (int r = 0; r < 4; ++r) {
            float ps = 0.f;
#pragma unroll
            for (int cc = 0; cc < 4; ++cc) {
              float p = __builtin_amdgcn_exp2f(sc[m][cc][r] - mrow[m][r]);
              sc[m][cc][r] = p;
              ps += p;
            }
#pragma unroll
            for (int off = 1; off < 16; off <<= 1) ps += __shfl_xor(ps, off);
            lsum[m][r] += ps;
          }

        // ---- P -> LDS (bf16) ----
#pragma unroll
        for (int m = 0; m < 2; ++m)
#pragma unroll
          for (int cc = 0; cc < 4; ++cc)
#pragma unroll
            for (int r = 0; r < 4; ++r)
              pw[(m * 16 + crow0 + r) * 72 + cc * 16 + cl] = f2bf(sc[m][cc][r]);

        // ---- PV ----
#pragma unroll
        for (int ks = 0; ks < 2; ++ks) {
          bf16x8 pf[2];
#pragma unroll
          for (int m = 0; m < 2; ++m)
            pf[m] = *reinterpret_cast<const bf16x8*>(pw + (m * 16 + cl) * 72 + ks * 32 + ck * 8);
#pragma unroll
          for (int dc = 0; dc < 4; ++dc) {
            const int vr = dc * 16 + cl;
            bf16x8 vf = *reinterpret_cast<const bf16x8*>(vb + vr * 64 + (((ks * 4 + ck) ^ (vr & 7)) * 8));
#pragma unroll
            for (int m = 0; m < 2; ++m)
              o[m][dc] = __builtin_amdgcn_mfma_f32_16x16x32_bf16(pf[m], vf, o[m][dc], 0, 0, 0);
          }
        }
      }

      __syncthreads();
      buf ^= 1;
    }

    // ---- epilogue ----
#pragma unroll
    for (int m = 0; m < 2; ++m) {
#pragma unroll
      for (int r = 0; r < 4; ++r) {
        float inv = 1.0f / lsum[m][r];
        int q = qminw + m * 16 + crow0 + r;
#pragma unroll
        for (int dc = 0; dc < 4; ++dc)
          attn_out[(size_t)(b * SS + q) * DD + h * DKK + dc * 16 + cl] = f2bf(o[m][dc][r] * inv);
      }
    }
  };

  process(NQT - 1 - pi);   // heavy tile first
  process(pi);             // then light tile
}

// ---------------- launch ----------------
extern "C" void kernel_launch(void* const* d_in, const int* in_sizes, int n_in,
                              void* d_out, int out_size, void* d_ws, size_t ws_size,
                              hipStream_t stream) {
  const float* x = (const float*)d_in[0];
  const float* w_q = (const float*)d_in[1];
  const float* w_k = (const float*)d_in[2];
  const float* w_v = (const float*)d_in[3];
  const float* w_o = (const float*)d_in[4];
  const float* b_o = (const float*)d_in[5];
  float* out = (float*)d_out;

  unsigned short* ws = (unsigned short*)d_ws;
  unsigned short* x_bf = ws;                               // 8192*1024
  unsigned short* w_qkv = x_bf + (size_t)MM * DD;          // 3072*1024
  unsigned short* w_obf = w_qkv + (size_t)NQKV * DD;       // 1024*1024
  unsigned short* qkv = w_obf + (size_t)DD * DD;           // 8192*3072
  unsigned short* vt = qkv + (size_t)MM * NQKV;            // B*H*DK*S = 8388608
  unsigned short* attn = vt + (size_t)BB * HH * DKK * SS;  // 8192*1024

  // converts
  cvt_kernel<<<(MM * DD / 4 + 255) / 256, 256, 0, stream>>>(x, x_bf, MM * DD / 4);
  cvt_kernel<<<(DD * DD / 4 + 255) / 256, 256, 0, stream>>>(w_q, w_qkv, DD * DD / 4);
  cvt_kernel<<<(DD * DD / 4 + 255) / 256, 256, 0, stream>>>(w_k, w_qkv + (size_t)DD * DD, DD * DD / 4);
  cvt_kernel<<<(DD * DD / 4 + 255) / 256, 256, 0, stream>>>(w_v, w_qkv + (size_t)2 * DD * DD, DD * DD / 4);
  cvt_kernel<<<(DD * DD / 4 + 255) / 256, 256, 0, stream>>>(w_o, w_obf, DD * DD / 4);

  // QKV projection: [8192,3072] = x_bf @ w_qkv^T (Q cols prescaled by 0.125*log2e)
  gemm_nt<2><<<dim3(NQKV / 128, MM / 128), 256, 0, stream>>>(x_bf, w_qkv, qkv, nullptr, NQKV, DD);

  // V transpose
  vt_kernel<<<dim3(SS / 64, HH, BB), 256, 0, stream>>>(qkv, vt);

  // attention (pair-balanced causal schedule)
  attn_kernel<<<dim3(NQT / 2, HH, BB), 256, 0, stream>>>(qkv, vt, attn);

  // output projection: [8192,1024] = attn @ w_o^T + b_o
  gemm_nt<0><<<dim3(DD / 128, MM / 128), 256, 0, stream>>>(attn, w_obf, out, b_o, DD, DD);
}

// Round 4
// 215.053 us; speedup vs baseline: 2.8385x; 1.1667x over previous
//
#include <hip/hip_runtime.h>
#include <hip/hip_bf16.h>
#include <math.h>

#define GLOBAL_AS __attribute__((address_space(1)))
#define LDS_AS __attribute__((address_space(3)))

typedef __bf16 bf16x8 __attribute__((ext_vector_type(8)));
typedef __bf16 bf16x4 __attribute__((ext_vector_type(4)));
typedef float f32x4 __attribute__((ext_vector_type(4)));
typedef unsigned short u16x8 __attribute__((ext_vector_type(8)));

static constexpr int BB = 4, SS = 2048, DD = 1024, HH = 16, DKK = 64;
static constexpr int MM = BB * SS;      // 8192 rows
static constexpr int NQKV = 3 * DD;     // 3072
static constexpr int NQT = SS / 128;    // 16 q-tiles

// ---------------- fp32 -> bf16 convert ----------------
__global__ __launch_bounds__(256) void cvt_kernel(const float* __restrict__ in,
                                                  __bf16* __restrict__ out,
                                                  int n4) {
  int i = blockIdx.x * blockDim.x + threadIdx.x;
  if (i < n4) {
    float4 v = reinterpret_cast<const float4*>(in)[i];
    bf16x4 o;
    o[0] = (__bf16)v.x; o[1] = (__bf16)v.y; o[2] = (__bf16)v.z; o[3] = (__bf16)v.w;
    *reinterpret_cast<bf16x4*>(out + (size_t)i * 4) = o;
  }
}

// ---------------- NT GEMM: C[M,N] = A[M,K] * B[N,K]^T ----------------
// MODE 0: f32 out + bias. MODE 1: bf16 out. MODE 2: bf16 out, cols<DD scaled by 0.125*log2(e).
template <int MODE>
__global__ __launch_bounds__(256) void gemm_nt(const unsigned short* __restrict__ A,
                                               const unsigned short* __restrict__ Bm,
                                               void* __restrict__ Cout,
                                               const float* __restrict__ bias,
                                               int Ndim, int K) {
  __shared__ __align__(16) unsigned short Asm[128 * 64];
  __shared__ __align__(16) unsigned short Bsm[128 * 64];
  const int tid = threadIdx.x, wv = tid >> 6, ln = tid & 63;
  const int bm0 = blockIdx.y * 128, bn0 = blockIdx.x * 128;
  const int wr = (wv >> 1) * 64, wc = (wv & 1) * 64;
  const int cl = ln & 15;        // A-row / B-col within 16
  const int ck = ln >> 4;        // k-chunk selector
  f32x4 acc[4][4] = {};

  for (int k0 = 0; k0 < K; k0 += 64) {
#pragma unroll
    for (int i = 0; i < 4; ++i) {
      int row = wv * 32 + i * 8 + (ln >> 3);
      int ch = (ln & 7) * 8;
      const unsigned short* ga = A + (size_t)(bm0 + row) * K + k0 + ch;
      const unsigned short* gb = Bm + (size_t)(bn0 + row) * K + k0 + ch;
      __builtin_amdgcn_global_load_lds((GLOBAL_AS void*)ga, (LDS_AS void*)(Asm + wv * 2048 + i * 512), 16, 0, 0);
      __builtin_amdgcn_global_load_lds((GLOBAL_AS void*)gb, (LDS_AS void*)(Bsm + wv * 2048 + i * 512), 16, 0, 0);
    }
    __syncthreads();
#pragma unroll
    for (int kk = 0; kk < 2; ++kk) {
      bf16x8 af[4], bfr[4];
#pragma unroll
      for (int m = 0; m < 4; ++m)
        af[m] = *reinterpret_cast<const bf16x8*>(Asm + (wr + m * 16 + cl) * 64 + kk * 32 + ck * 8);
#pragma unroll
      for (int n = 0; n < 4; ++n)
        bfr[n] = *reinterpret_cast<const bf16x8*>(Bsm + (wc + n * 16 + cl) * 64 + kk * 32 + ck * 8);
#pragma unroll
      for (int m = 0; m < 4; ++m)
#pragma unroll
        for (int n = 0; n < 4; ++n)
          acc[m][n] = __builtin_amdgcn_mfma_f32_16x16x32_bf16(af[m], bfr[n], acc[m][n], 0, 0, 0);
    }
    __syncthreads();
  }
  const int crow0 = ck * 4;
#pragma unroll
  for (int m = 0; m < 4; ++m) {
#pragma unroll
    for (int n = 0; n < 4; ++n) {
      int col = bn0 + wc + n * 16 + cl;
#pragma unroll
      for (int r = 0; r < 4; ++r) {
        int row = bm0 + wr + m * 16 + crow0 + r;
        float v = acc[m][n][r];
        if constexpr (MODE == 0) {
          ((float*)Cout)[(size_t)row * Ndim + col] = v + bias[col];
        } else {
          if constexpr (MODE == 2) { if (col < DD) v *= 0.18033688011112042f; } // 0.125*log2(e)
          ((__bf16*)Cout)[(size_t)row * Ndim + col] = (__bf16)v;
        }
      }
    }
  }
}

// ---------------- V transpose: qkv V-part -> Vt[b,h,dk,s] ----------------
__global__ __launch_bounds__(256) void vt_kernel(const unsigned short* __restrict__ qkv,
                                                 unsigned short* __restrict__ vt) {
  const int st = blockIdx.x, h = blockIdx.y, b = blockIdx.z;
  const int s0 = st * 64;
  __shared__ __align__(16) unsigned short tile[64][72];
  const int t = threadIdx.x;
  const int rs = t >> 2;            // 0..63
  const int c4 = (t & 3) * 16;      // 0,16,32,48
#pragma unroll
  for (int j2 = 0; j2 < 2; ++j2) {
    u16x8 v = *reinterpret_cast<const u16x8*>(qkv + (size_t)(b * SS + s0 + rs) * NQKV + 2 * DD + h * DKK + c4 + j2 * 8);
#pragma unroll
    for (int j = 0; j < 8; ++j) tile[rs][c4 + j2 * 8 + j] = v[j];
  }
  __syncthreads();
#pragma unroll
  for (int j2 = 0; j2 < 2; ++j2) {
    u16x8 v;
#pragma unroll
    for (int j = 0; j < 8; ++j) v[j] = tile[c4 + j2 * 8 + j][rs];
    *reinterpret_cast<u16x8*>(vt + ((size_t)((b * HH + h) * 64 + rs)) * SS + s0 + c4 + j2 * 8) = v;
  }
}

// ---------------- causal flash attention ----------------
// grid (NQT/2, H, B); block i does q-tiles (NQT-1-i) then (i)  -> balanced 34 tile-units.
// 4 waves, each owns 32 q-rows. K/Vt tiles (64x64) double-buffered in LDS, XOR chunk-swizzle.
// Q prescaled by 0.125*log2(e); softmax in exp2 space; wave-coarse defer-rescale THR=8;
// row-sums via ones-MFMA (no shuffle-sum); native bf16 cvt for P.
__global__ __launch_bounds__(256) void attn_kernel(const unsigned short* __restrict__ qkv,
                                                   const unsigned short* __restrict__ vt,
                                                   unsigned short* __restrict__ attn_out) {
  const int pi = blockIdx.x, h = blockIdx.y, b = blockIdx.z;
  const int tid = threadIdx.x, wv = tid >> 6, ln = tid & 63;
  const int cl = ln & 15, ck = ln >> 4;
  const int crow0 = ck * 4;
  const int bh = b * HH + h;

  __shared__ __align__(16) unsigned short Ks[2][64 * 64];
  __shared__ __align__(16) unsigned short Vs[2][64 * 64];
  __shared__ __align__(16) unsigned short Pl[4][32 * 72];
  __bf16* pw = (__bf16*)&Pl[wv][0];

  bf16x8 vones;
#pragma unroll
  for (int j = 0; j < 8; ++j) vones[j] = (__bf16)1.0f;

  auto stage = [&](int bsel, int kv0s) {
#pragma unroll
    for (int i = 0; i < 2; ++i) {
      int idx = wv * 2 + i;
      int row = idx * 8 + (ln >> 3);
      int sch = (ln & 7) ^ (row & 7);   // pre-swizzled source chunk
      const unsigned short* gk = qkv + ((size_t)(b * SS + kv0s + row) * NQKV + DD + h * DKK + sch * 8);
      __builtin_amdgcn_global_load_lds((GLOBAL_AS void*)gk, (LDS_AS void*)(&Ks[bsel][idx * 512]), 16, 0, 0);
      const unsigned short* gv = vt + ((size_t)(bh * 64 + row) * SS + kv0s + sch * 8);
      __builtin_amdgcn_global_load_lds((GLOBAL_AS void*)gv, (LDS_AS void*)(&Vs[bsel][idx * 512]), 16, 0, 0);
    }
  };

  auto process = [&](int qt) {
    const int q0 = qt * 128;
    const int qminw = q0 + wv * 32;
    const int qmaxw = qminw + 31;

    bf16x8 qf[2][2];
#pragma unroll
    for (int m = 0; m < 2; ++m)
#pragma unroll
      for (int kk = 0; kk < 2; ++kk)
        qf[m][kk] = *reinterpret_cast<const bf16x8*>(
            qkv + (size_t)(b * SS + qminw + m * 16 + cl) * NQKV + h * DKK + kk * 32 + ck * 8);

    f32x4 o[2][4] = {};
    f32x4 lsum[2] = {};
    float mrow[2][4];
#pragma unroll
    for (int m = 0; m < 2; ++m)
#pragma unroll
      for (int r = 0; r < 4; ++r) mrow[m][r] = -INFINITY;

    const int nt = 2 * qt + 2;
    stage(0, 0);
    __syncthreads();
    int buf = 0;

    for (int t = 0; t < nt; ++t) {
      const int kv0 = t * 64;
      if (t + 1 < nt) stage(buf ^ 1, (t + 1) * 64);

      if (kv0 <= qmaxw) {
        const unsigned short* kb = &Ks[buf][0];
        const unsigned short* vb = &Vs[buf][0];

        // ---- QK^T (logits already in log2 space) ----
        f32x4 sc[2][4];
        __builtin_amdgcn_s_setprio(1);
#pragma unroll
        for (int cc = 0; cc < 4; ++cc) {
          const int kvr = cc * 16 + cl;
          bf16x8 kf0 = *reinterpret_cast<const bf16x8*>(kb + kvr * 64 + ((ck ^ (kvr & 7)) * 8));
          bf16x8 kf1 = *reinterpret_cast<const bf16x8*>(kb + kvr * 64 + (((4 + ck) ^ (kvr & 7)) * 8));
#pragma unroll
          for (int m = 0; m < 2; ++m) {
            f32x4 z = {};
            z = __builtin_amdgcn_mfma_f32_16x16x32_bf16(qf[m][0], kf0, z, 0, 0, 0);
            z = __builtin_amdgcn_mfma_f32_16x16x32_bf16(qf[m][1], kf1, z, 0, 0, 0);
            sc[m][cc] = z;
          }
        }
        __builtin_amdgcn_s_setprio(0);

        // ---- causal mask (only near the diagonal) ----
        if (kv0 + 63 > qminw) {
#pragma unroll
          for (int cc = 0; cc < 4; ++cc) {
            const int col = kv0 + cc * 16 + cl;
#pragma unroll
            for (int m = 0; m < 2; ++m) {
              const int qr = qminw + m * 16 + crow0;
#pragma unroll
              for (int r = 0; r < 4; ++r)
                sc[m][cc][r] = (col <= qr + r) ? sc[m][cc][r] : -INFINITY;
            }
          }
        }

        // ---- wave-coarse defer-max check ----
        float tl = -INFINITY;
#pragma unroll
        for (int m = 0; m < 2; ++m)
#pragma unroll
          for (int cc = 0; cc < 4; ++cc)
#pragma unroll
            for (int r = 0; r < 4; ++r) tl = fmaxf(tl, sc[m][cc][r]);
#pragma unroll
        for (int off = 1; off < 64; off <<= 1) tl = fmaxf(tl, __shfl_xor(tl, off));
        float mn_all = mrow[0][0];
#pragma unroll
        for (int m = 0; m < 2; ++m)
#pragma unroll
          for (int r = 0; r < 4; ++r) mn_all = fminf(mn_all, mrow[m][r]);
        mn_all = fminf(mn_all, __shfl_xor(mn_all, 16));
        mn_all = fminf(mn_all, __shfl_xor(mn_all, 32));

        if (tl - mn_all > 8.0f) {  // rescale path (wave-uniform)
#pragma unroll
          for (int m = 0; m < 2; ++m)
#pragma unroll
            for (int r = 0; r < 4; ++r) {
              float t0 = fmaxf(fmaxf(sc[m][0][r], sc[m][1][r]), fmaxf(sc[m][2][r], sc[m][3][r]));
#pragma unroll
              for (int off = 1; off < 16; off <<= 1) t0 = fmaxf(t0, __shfl_xor(t0, off));
              float mn = fmaxf(mrow[m][r], t0);
              float al = __builtin_amdgcn_exp2f(mrow[m][r] - mn);
              mrow[m][r] = mn;
              lsum[m][r] *= al;
#pragma unroll
              for (int dc = 0; dc < 4; ++dc) o[m][dc][r] *= al;
            }
        }

        // ---- P = exp2(S - m) -> LDS (bf16, native cvt) ----
#pragma unroll
        for (int m = 0; m < 2; ++m)
#pragma unroll
          for (int cc = 0; cc < 4; ++cc)
#pragma unroll
            for (int r = 0; r < 4; ++r)
              pw[(m * 16 + crow0 + r) * 72 + cc * 16 + cl] =
                  (__bf16)__builtin_amdgcn_exp2f(sc[m][cc][r] - mrow[m][r]);

        // ---- PV + row-sum via ones-MFMA ----
        __builtin_amdgcn_s_setprio(1);
#pragma unroll
        for (int ks = 0; ks < 2; ++ks) {
          bf16x8 pf[2];
#pragma unroll
          for (int m = 0; m < 2; ++m) {
            pf[m] = *reinterpret_cast<const bf16x8*>(pw + (m * 16 + cl) * 72 + ks * 32 + ck * 8);
            lsum[m] = __builtin_amdgcn_mfma_f32_16x16x32_bf16(pf[m], vones, lsum[m], 0, 0, 0);
          }
#pragma unroll
          for (int dc = 0; dc < 4; ++dc) {
            const int vr = dc * 16 + cl;
            bf16x8 vf = *reinterpret_cast<const bf16x8*>(vb + vr * 64 + (((ks * 4 + ck) ^ (vr & 7)) * 8));
#pragma unroll
            for (int m = 0; m < 2; ++m)
              o[m][dc] = __builtin_amdgcn_mfma_f32_16x16x32_bf16(pf[m], vf, o[m][dc], 0, 0, 0);
          }
        }
        __builtin_amdgcn_s_setprio(0);
      }

      __syncthreads();
      buf ^= 1;
    }

    // ---- epilogue ----
#pragma unroll
    for (int m = 0; m < 2; ++m) {
#pragma unroll
      for (int r = 0; r < 4; ++r) {
        float inv = 1.0f / lsum[m][r];
        int q = qminw + m * 16 + crow0 + r;
#pragma unroll
        for (int dc = 0; dc < 4; ++dc)
          ((__bf16*)attn_out)[(size_t)(b * SS + q) * DD + h * DKK + dc * 16 + cl] =
              (__bf16)(o[m][dc][r] * inv);
      }
    }
  };

  process(NQT - 1 - pi);   // heavy tile first
  process(pi);             // then light tile
}

// ---------------- launch ----------------
extern "C" void kernel_launch(void* const* d_in, const int* in_sizes, int n_in,
                              void* d_out, int out_size, void* d_ws, size_t ws_size,
                              hipStream_t stream) {
  const float* x = (const float*)d_in[0];
  const float* w_q = (const float*)d_in[1];
  const float* w_k = (const float*)d_in[2];
  const float* w_v = (const float*)d_in[3];
  const float* w_o = (const float*)d_in[4];
  const float* b_o = (const float*)d_in[5];
  float* out = (float*)d_out;

  unsigned short* ws = (unsigned short*)d_ws;
  unsigned short* x_bf = ws;                               // 8192*1024
  unsigned short* w_qkv = x_bf + (size_t)MM * DD;          // 3072*1024
  unsigned short* w_obf = w_qkv + (size_t)NQKV * DD;       // 1024*1024
  unsigned short* qkv = w_obf + (size_t)DD * DD;           // 8192*3072
  unsigned short* vt = qkv + (size_t)MM * NQKV;            // B*H*DK*S = 8388608
  unsigned short* attn = vt + (size_t)BB * HH * DKK * SS;  // 8192*1024

  // converts
  cvt_kernel<<<(MM * DD / 4 + 255) / 256, 256, 0, stream>>>(x, (__bf16*)x_bf, MM * DD / 4);
  cvt_kernel<<<(DD * DD / 4 + 255) / 256, 256, 0, stream>>>(w_q, (__bf16*)w_qkv, DD * DD / 4);
  cvt_kernel<<<(DD * DD / 4 + 255) / 256, 256, 0, stream>>>(w_k, (__bf16*)(w_qkv + (size_t)DD * DD), DD * DD / 4);
  cvt_kernel<<<(DD * DD / 4 + 255) / 256, 256, 0, stream>>>(w_v, (__bf16*)(w_qkv + (size_t)2 * DD * DD), DD * DD / 4);
  cvt_kernel<<<(DD * DD / 4 + 255) / 256, 256, 0, stream>>>(w_o, (__bf16*)w_obf, DD * DD / 4);

  // QKV projection: [8192,3072] = x_bf @ w_qkv^T (Q cols prescaled by 0.125*log2e)
  gemm_nt<2><<<dim3(NQKV / 128, MM / 128), 256, 0, stream>>>(x_bf, w_qkv, qkv, nullptr, NQKV, DD);

  // V transpose
  vt_kernel<<<dim3(SS / 64, HH, BB), 256, 0, stream>>>(qkv, vt);

  // attention (pair-balanced causal schedule)
  attn_kernel<<<dim3(NQT / 2, HH, BB), 256, 0, stream>>>(qkv, vt, attn);

  // output projection: [8192,1024] = attn @ w_o^T + b_o
  gemm_nt<0><<<dim3(DD / 128, MM / 128), 256, 0, stream>>>(attn, w_obf, out, b_o, DD, DD);
}

// Round 5
// 208.411 us; speedup vs baseline: 2.9289x; 1.0319x over previous
//
#include <hip/hip_runtime.h>
#include <hip/hip_bf16.h>
#include <math.h>

#define GLOBAL_AS __attribute__((address_space(1)))
#define LDS_AS __attribute__((address_space(3)))

typedef __bf16 bf16x8 __attribute__((ext_vector_type(8)));
typedef __bf16 bf16x4 __attribute__((ext_vector_type(4)));
typedef float f32x4 __attribute__((ext_vector_type(4)));
typedef unsigned short u16x8 __attribute__((ext_vector_type(8)));

static constexpr int BB = 4, SS = 2048, DD = 1024, HH = 16, DKK = 64;
static constexpr int MM = BB * SS;      // 8192 rows
static constexpr int NQKV = 3 * DD;     // 3072
static constexpr int NQT = SS / 128;    // 16 q-tiles

// ---------------- fp32 -> bf16 convert ----------------
__global__ __launch_bounds__(256) void cvt_kernel(const float* __restrict__ in,
                                                  __bf16* __restrict__ out,
                                                  int n4) {
  int i = blockIdx.x * blockDim.x + threadIdx.x;
  if (i < n4) {
    float4 v = reinterpret_cast<const float4*>(in)[i];
    bf16x4 o;
    o[0] = (__bf16)v.x; o[1] = (__bf16)v.y; o[2] = (__bf16)v.z; o[3] = (__bf16)v.w;
    *reinterpret_cast<bf16x4*>(out + (size_t)i * 4) = o;
  }
}

// ---------------- phase-pipelined NT GEMM: C[M,N] = A[M,K] * B[N,K]^T ----------------
// BM=128, BN=256, BK=64. 8 waves (2M x 4N), per-wave 64x64 output.
// LDS: 2 buffers x 2 K-halves; A-unit 128x32 (8KB), B-unit 256x32 (16KB) = 96KB.
// 2 phases per K-tile (one per K-half), 16 MFMA/phase, counted vmcnt(6) (T3+T4),
// 16B-chunk XOR swizzle via pre-swizzled global source (T2), setprio around MFMA (T5).
// MODE 0: f32 out + bias. MODE 2: bf16 out, cols<DD scaled by 0.125*log2(e).
template <int MODE>
__global__ __launch_bounds__(512, 1) void gemm8p(const unsigned short* __restrict__ A,
                                                 const unsigned short* __restrict__ Bm,
                                                 void* __restrict__ Cout,
                                                 const float* __restrict__ bias,
                                                 int Ndim, int K) {
  __shared__ __align__(16) unsigned short Asm[2 * 2 * 4096];   // [buf][kk][128*32]
  __shared__ __align__(16) unsigned short Bsm[2 * 2 * 8192];   // [buf][kk][256*32]
  const int tid = threadIdx.x, wid = tid >> 6, ln = tid & 63;
  const int wm = wid >> 2, wn = wid & 3;
  const int cl = ln & 15, ck = ln >> 4;

  // XCD-aware bijective swizzle (nwg % 8 == 0 for both launch configs)
  const int gx = gridDim.x;
  const int nwg = gx * gridDim.y;
  const int qch = nwg >> 3;
  int lid = blockIdx.y * gx + blockIdx.x;
  lid = (lid & 7) * qch + (lid >> 3);
  const int bn0 = (lid % gx) * 256;
  const int bm0 = (lid / gx) * 128;

  const int KT = K >> 6;
  const int sr = tid >> 2;                       // staging row 0..127
  const int scol = ((tid & 3) ^ (sr & 3)) << 3;  // pre-swizzled source col (shorts)
  const int sc8 = (ck ^ (cl & 3)) << 3;          // swizzled frag-read chunk (shorts)

  f32x4 acc[4][4] = {};

  auto stage_group = [&](int buf, int kt, int kk) {  // 3 loads: A-half + B-half(2)
    const int k0 = kt * 64 + kk * 32;
    const unsigned short* ga = A + (size_t)(bm0 + sr) * K + k0 + scol;
    __builtin_amdgcn_global_load_lds((GLOBAL_AS void*)ga,
        (LDS_AS void*)(Asm + (buf * 2 + kk) * 4096 + wid * 512), 16, 0, 0);
#pragma unroll
    for (int j = 0; j < 2; ++j) {
      const unsigned short* gb = Bm + (size_t)(bn0 + j * 128 + sr) * K + k0 + scol;
      __builtin_amdgcn_global_load_lds((GLOBAL_AS void*)gb,
          (LDS_AS void*)(Bsm + (buf * 2 + kk) * 8192 + j * 4096 + wid * 512), 16, 0, 0);
    }
  };

  auto phase = [&](int p, int kk, int g_buf, int g_kt, int g_kk, bool g_issue, int vm) {
    bf16x8 af[4], bfr[4];
    const unsigned short* ab = Asm + (p * 2 + kk) * 4096;
    const unsigned short* bb = Bsm + (p * 2 + kk) * 8192;
#pragma unroll
    for (int mf = 0; mf < 4; ++mf)
      af[mf] = *reinterpret_cast<const bf16x8*>(ab + (wm * 64 + mf * 16 + cl) * 32 + sc8);
#pragma unroll
    for (int nf = 0; nf < 4; ++nf)
      bfr[nf] = *reinterpret_cast<const bf16x8*>(bb + (wn * 64 + nf * 16 + cl) * 32 + sc8);
    if (g_issue) stage_group(g_buf, g_kt, g_kk);
    __builtin_amdgcn_s_barrier();
    __builtin_amdgcn_s_setprio(1);
#pragma unroll
    for (int mf = 0; mf < 4; ++mf)
#pragma unroll
      for (int nf = 0; nf < 4; ++nf)
        acc[mf][nf] = __builtin_amdgcn_mfma_f32_16x16x32_bf16(af[mf], bfr[nf], acc[mf][nf], 0, 0, 0);
    __builtin_amdgcn_s_setprio(0);
    if (vm == 6)      asm volatile("s_waitcnt vmcnt(6)" ::: "memory");
    else if (vm == 3) asm volatile("s_waitcnt vmcnt(3)" ::: "memory");
    else if (vm == 0) asm volatile("s_waitcnt vmcnt(0)" ::: "memory");
    __builtin_amdgcn_s_barrier();
  };

  // prologue: groups (0,kk0), (0,kk1), (1,kk0); wait so (0,kk0) is resident
  stage_group(0, 0, 0);
  stage_group(0, 0, 1);
  stage_group(1, 1, 0);
  asm volatile("s_waitcnt vmcnt(6)" ::: "memory");
  __builtin_amdgcn_s_barrier();

  for (int kt = 0; kt < KT; ++kt) {
    const int p = kt & 1;
    const bool i0 = (kt + 1 < KT);
    const bool i1 = (kt + 2 < KT);
    // phase 0: consume (p,kk0); issue (kt+1,kk1) -> buf p^1; ensure (kt,kk1) for next phase
    phase(p, 0, p ^ 1, kt + 1, 1, i0, i0 ? 6 : 0);
    // phase 1: consume (p,kk1); issue (kt+2,kk0) -> buf p; ensure (kt+1,kk0) for next iter
    phase(p, 1, p, kt + 2, 0, i1, (kt < KT - 1) ? (i1 ? 6 : 3) : -1);
  }

  // epilogue
#pragma unroll
  for (int mf = 0; mf < 4; ++mf) {
#pragma unroll
    for (int nf = 0; nf < 4; ++nf) {
      const int col = bn0 + wn * 64 + nf * 16 + cl;
#pragma unroll
      for (int r = 0; r < 4; ++r) {
        const int row = bm0 + wm * 64 + mf * 16 + ck * 4 + r;
        float v = acc[mf][nf][r];
        if constexpr (MODE == 0) {
          ((float*)Cout)[(size_t)row * Ndim + col] = v + bias[col];
        } else {
          if constexpr (MODE == 2) { if (col < DD) v *= 0.18033688011112042f; } // 0.125*log2(e)
          ((__bf16*)Cout)[(size_t)row * Ndim + col] = (__bf16)v;
        }
      }
    }
  }
}

// ---------------- V transpose: qkv V-part -> Vt[b,h,dk,s] ----------------
__global__ __launch_bounds__(256) void vt_kernel(const unsigned short* __restrict__ qkv,
                                                 unsigned short* __restrict__ vt) {
  const int st = blockIdx.x, h = blockIdx.y, b = blockIdx.z;
  const int s0 = st * 64;
  __shared__ __align__(16) unsigned short tile[64][72];
  const int t = threadIdx.x;
  const int rs = t >> 2;            // 0..63
  const int c4 = (t & 3) * 16;      // 0,16,32,48
#pragma unroll
  for (int j2 = 0; j2 < 2; ++j2) {
    u16x8 v = *reinterpret_cast<const u16x8*>(qkv + (size_t)(b * SS + s0 + rs) * NQKV + 2 * DD + h * DKK + c4 + j2 * 8);
#pragma unroll
    for (int j = 0; j < 8; ++j) tile[rs][c4 + j2 * 8 + j] = v[j];
  }
  __syncthreads();
#pragma unroll
  for (int j2 = 0; j2 < 2; ++j2) {
    u16x8 v;
#pragma unroll
    for (int j = 0; j < 8; ++j) v[j] = tile[c4 + j2 * 8 + j][rs];
    *reinterpret_cast<u16x8*>(vt + ((size_t)((b * HH + h) * 64 + rs)) * SS + s0 + c4 + j2 * 8) = v;
  }
}

// ---------------- causal flash attention ----------------
// grid (NQT/2, H, B); block i does q-tiles (NQT-1-i) then (i)  -> balanced 34 tile-units.
// 4 waves, each owns 32 q-rows. K/Vt tiles (64x64) double-buffered in LDS, XOR chunk-swizzle.
// Q prescaled by 0.125*log2(e); softmax in exp2 space; wave-coarse defer-rescale THR=8;
// row-sums via ones-MFMA (no shuffle-sum); native bf16 cvt for P.
__global__ __launch_bounds__(256) void attn_kernel(const unsigned short* __restrict__ qkv,
                                                   const unsigned short* __restrict__ vt,
                                                   unsigned short* __restrict__ attn_out) {
  const int pi = blockIdx.x, h = blockIdx.y, b = blockIdx.z;
  const int tid = threadIdx.x, wv = tid >> 6, ln = tid & 63;
  const int cl = ln & 15, ck = ln >> 4;
  const int crow0 = ck * 4;
  const int bh = b * HH + h;

  __shared__ __align__(16) unsigned short Ks[2][64 * 64];
  __shared__ __align__(16) unsigned short Vs[2][64 * 64];
  __shared__ __align__(16) unsigned short Pl[4][32 * 72];
  __bf16* pw = (__bf16*)&Pl[wv][0];

  bf16x8 vones;
#pragma unroll
  for (int j = 0; j < 8; ++j) vones[j] = (__bf16)1.0f;

  auto stage = [&](int bsel, int kv0s) {
#pragma unroll
    for (int i = 0; i < 2; ++i) {
      int idx = wv * 2 + i;
      int row = idx * 8 + (ln >> 3);
      int sch = (ln & 7) ^ (row & 7);   // pre-swizzled source chunk
      const unsigned short* gk = qkv + ((size_t)(b * SS + kv0s + row) * NQKV + DD + h * DKK + sch * 8);
      __builtin_amdgcn_global_load_lds((GLOBAL_AS void*)gk, (LDS_AS void*)(&Ks[bsel][idx * 512]), 16, 0, 0);
      const unsigned short* gv = vt + ((size_t)(bh * 64 + row) * SS + kv0s + sch * 8);
      __builtin_amdgcn_global_load_lds((GLOBAL_AS void*)gv, (LDS_AS void*)(&Vs[bsel][idx * 512]), 16, 0, 0);
    }
  };

  auto process = [&](int qt) {
    const int q0 = qt * 128;
    const int qminw = q0 + wv * 32;
    const int qmaxw = qminw + 31;

    bf16x8 qf[2][2];
#pragma unroll
    for (int m = 0; m < 2; ++m)
#pragma unroll
      for (int kk = 0; kk < 2; ++kk)
        qf[m][kk] = *reinterpret_cast<const bf16x8*>(
            qkv + (size_t)(b * SS + qminw + m * 16 + cl) * NQKV + h * DKK + kk * 32 + ck * 8);

    f32x4 o[2][4] = {};
    f32x4 lsum[2] = {};
    float mrow[2][4];
#pragma unroll
    for (int m = 0; m < 2; ++m)
#pragma unroll
      for (int r = 0; r < 4; ++r) mrow[m][r] = -INFINITY;

    const int nt = 2 * qt + 2;
    stage(0, 0);
    __syncthreads();
    int buf = 0;

    for (int t = 0; t < nt; ++t) {
      const int kv0 = t * 64;
      if (t + 1 < nt) stage(buf ^ 1, (t + 1) * 64);

      if (kv0 <= qmaxw) {
        const unsigned short* kb = &Ks[buf][0];
        const unsigned short* vb = &Vs[buf][0];

        // ---- QK^T (logits already in log2 space) ----
        f32x4 sc[2][4];
        __builtin_amdgcn_s_setprio(1);
#pragma unroll
        for (int cc = 0; cc < 4; ++cc) {
          const int kvr = cc * 16 + cl;
          bf16x8 kf0 = *reinterpret_cast<const bf16x8*>(kb + kvr * 64 + ((ck ^ (kvr & 7)) * 8));
          bf16x8 kf1 = *reinterpret_cast<const bf16x8*>(kb + kvr * 64 + (((4 + ck) ^ (kvr & 7)) * 8));
#pragma unroll
          for (int m = 0; m < 2; ++m) {
            f32x4 z = {};
            z = __builtin_amdgcn_mfma_f32_16x16x32_bf16(qf[m][0], kf0, z, 0, 0, 0);
            z = __builtin_amdgcn_mfma_f32_16x16x32_bf16(qf[m][1], kf1, z, 0, 0, 0);
            sc[m][cc] = z;
          }
        }
        __builtin_amdgcn_s_setprio(0);

        // ---- causal mask (only near the diagonal) ----
        if (kv0 + 63 > qminw) {
#pragma unroll
          for (int cc = 0; cc < 4; ++cc) {
            const int col = kv0 + cc * 16 + cl;
#pragma unroll
            for (int m = 0; m < 2; ++m) {
              const int qr = qminw + m * 16 + crow0;
#pragma unroll
              for (int r = 0; r < 4; ++r)
                sc[m][cc][r] = (col <= qr + r) ? sc[m][cc][r] : -INFINITY;
            }
          }
        }

        // ---- wave-coarse defer-max check ----
        float tl = -INFINITY;
#pragma unroll
        for (int m = 0; m < 2; ++m)
#pragma unroll
          for (int cc = 0; cc < 4; ++cc)
#pragma unroll
            for (int r = 0; r < 4; ++r) tl = fmaxf(tl, sc[m][cc][r]);
#pragma unroll
        for (int off = 1; off < 64; off <<= 1) tl = fmaxf(tl, __shfl_xor(tl, off));
        float mn_all = mrow[0][0];
#pragma unroll
        for (int m = 0; m < 2; ++m)
#pragma unroll
          for (int r = 0; r < 4; ++r) mn_all = fminf(mn_all, mrow[m][r]);
        mn_all = fminf(mn_all, __shfl_xor(mn_all, 16));
        mn_all = fminf(mn_all, __shfl_xor(mn_all, 32));

        if (tl - mn_all > 8.0f) {  // rescale path (wave-uniform)
#pragma unroll
          for (int m = 0; m < 2; ++m)
#pragma unroll
            for (int r = 0; r < 4; ++r) {
              float t0 = fmaxf(fmaxf(sc[m][0][r], sc[m][1][r]), fmaxf(sc[m][2][r], sc[m][3][r]));
#pragma unroll
              for (int off = 1; off < 16; off <<= 1) t0 = fmaxf(t0, __shfl_xor(t0, off));
              float mn = fmaxf(mrow[m][r], t0);
              float al = __builtin_amdgcn_exp2f(mrow[m][r] - mn);
              mrow[m][r] = mn;
              lsum[m][r] *= al;
#pragma unroll
              for (int dc = 0; dc < 4; ++dc) o[m][dc][r] *= al;
            }
        }

        // ---- P = exp2(S - m) -> LDS (bf16, native cvt) ----
#pragma unroll
        for (int m = 0; m < 2; ++m)
#pragma unroll
          for (int cc = 0; cc < 4; ++cc)
#pragma unroll
            for (int r = 0; r < 4; ++r)
              pw[(m * 16 + crow0 + r) * 72 + cc * 16 + cl] =
                  (__bf16)__builtin_amdgcn_exp2f(sc[m][cc][r] - mrow[m][r]);

        // ---- PV + row-sum via ones-MFMA ----
        __builtin_amdgcn_s_setprio(1);
#pragma unroll
        for (int ks = 0; ks < 2; ++ks) {
          bf16x8 pf[2];
#pragma unroll
          for (int m = 0; m < 2; ++m) {
            pf[m] = *reinterpret_cast<const bf16x8*>(pw + (m * 16 + cl) * 72 + ks * 32 + ck * 8);
            lsum[m] = __builtin_amdgcn_mfma_f32_16x16x32_bf16(pf[m], vones, lsum[m], 0, 0, 0);
          }
#pragma unroll
          for (int dc = 0; dc < 4; ++dc) {
            const int vr = dc * 16 + cl;
            bf16x8 vf = *reinterpret_cast<const bf16x8*>(vb + vr * 64 + (((ks * 4 + ck) ^ (vr & 7)) * 8));
#pragma unroll
            for (int m = 0; m < 2; ++m)
              o[m][dc] = __builtin_amdgcn_mfma_f32_16x16x32_bf16(pf[m], vf, o[m][dc], 0, 0, 0);
          }
        }
        __builtin_amdgcn_s_setprio(0);
      }

      __syncthreads();
      buf ^= 1;
    }

    // ---- epilogue ----
#pragma unroll
    for (int m = 0; m < 2; ++m) {
#pragma unroll
      for (int r = 0; r < 4; ++r) {
        float inv = 1.0f / lsum[m][r];
        int q = qminw + m * 16 + crow0 + r;
#pragma unroll
        for (int dc = 0; dc < 4; ++dc)
          ((__bf16*)attn_out)[(size_t)(b * SS + q) * DD + h * DKK + dc * 16 + cl] =
              (__bf16)(o[m][dc][r] * inv);
      }
    }
  };

  process(NQT - 1 - pi);   // heavy tile first
  process(pi);             // then light tile
}

// ---------------- launch ----------------
extern "C" void kernel_launch(void* const* d_in, const int* in_sizes, int n_in,
                              void* d_out, int out_size, void* d_ws, size_t ws_size,
                              hipStream_t stream) {
  const float* x = (const float*)d_in[0];
  const float* w_q = (const float*)d_in[1];
  const float* w_k = (const float*)d_in[2];
  const float* w_v = (const float*)d_in[3];
  const float* w_o = (const float*)d_in[4];
  const float* b_o = (const float*)d_in[5];
  float* out = (float*)d_out;

  unsigned short* ws = (unsigned short*)d_ws;
  unsigned short* x_bf = ws;                               // 8192*1024
  unsigned short* w_qkv = x_bf + (size_t)MM * DD;          // 3072*1024
  unsigned short* w_obf = w_qkv + (size_t)NQKV * DD;       // 1024*1024
  unsigned short* qkv = w_obf + (size_t)DD * DD;           // 8192*3072
  unsigned short* vt = qkv + (size_t)MM * NQKV;            // B*H*DK*S = 8388608
  unsigned short* attn = vt + (size_t)BB * HH * DKK * SS;  // 8192*1024

  // converts
  cvt_kernel<<<(MM * DD / 4 + 255) / 256, 256, 0, stream>>>(x, (__bf16*)x_bf, MM * DD / 4);
  cvt_kernel<<<(DD * DD / 4 + 255) / 256, 256, 0, stream>>>(w_q, (__bf16*)w_qkv, DD * DD / 4);
  cvt_kernel<<<(DD * DD / 4 + 255) / 256, 256, 0, stream>>>(w_k, (__bf16*)(w_qkv + (size_t)DD * DD), DD * DD / 4);
  cvt_kernel<<<(DD * DD / 4 + 255) / 256, 256, 0, stream>>>(w_v, (__bf16*)(w_qkv + (size_t)2 * DD * DD), DD * DD / 4);
  cvt_kernel<<<(DD * DD / 4 + 255) / 256, 256, 0, stream>>>(w_o, (__bf16*)w_obf, DD * DD / 4);

  // QKV projection: [8192,3072] = x_bf @ w_qkv^T (Q cols prescaled by 0.125*log2e)
  gemm8p<2><<<dim3(NQKV / 256, MM / 128), 512, 0, stream>>>(x_bf, w_qkv, qkv, nullptr, NQKV, DD);

  // V transpose
  vt_kernel<<<dim3(SS / 64, HH, BB), 256, 0, stream>>>(qkv, vt);

  // attention (pair-balanced causal schedule)
  attn_kernel<<<dim3(NQT / 2, HH, BB), 256, 0, stream>>>(qkv, vt, attn);

  // output projection: [8192,1024] = attn @ w_o^T + b_o
  gemm8p<0><<<dim3(DD / 256, MM / 128), 512, 0, stream>>>(attn, w_obf, out, b_o, DD, DD);
}

// Round 8
// 188.897 us; speedup vs baseline: 3.2315x; 1.1033x over previous
//
#include <hip/hip_runtime.h>
#include <hip/hip_bf16.h>
#include <math.h>

#define GLOBAL_AS __attribute__((address_space(1)))
#define LDS_AS __attribute__((address_space(3)))

typedef __bf16 bf16x8 __attribute__((ext_vector_type(8)));
typedef __bf16 bf16x4 __attribute__((ext_vector_type(4)));
typedef float f32x4 __attribute__((ext_vector_type(4)));
typedef float f32x16 __attribute__((ext_vector_type(16)));
typedef unsigned short u16x8 __attribute__((ext_vector_type(8)));

static constexpr int BB = 4, SS = 2048, DD = 1024, HH = 16, DKK = 64;
static constexpr int MM = BB * SS;      // 8192 rows
static constexpr int NQKV = 3 * DD;     // 3072
static constexpr int NQT = SS / 128;    // 16 q-tiles

__device__ inline unsigned int cvt_pk_bf16(float lo, float hi) {
  unsigned int r;
  asm("v_cvt_pk_bf16_f32 %0, %1, %2" : "=v"(r) : "v"(lo), "v"(hi));
  return r;
}

// ---------------- fp32 -> bf16 convert (x) ----------------
__global__ __launch_bounds__(256) void cvt_kernel(const float* __restrict__ in,
                                                  __bf16* __restrict__ out,
                                                  int n4) {
  int i = blockIdx.x * blockDim.x + threadIdx.x;
  if (i < n4) {
    float4 v = reinterpret_cast<const float4*>(in)[i];
    bf16x4 o;
    o[0] = (__bf16)v.x; o[1] = (__bf16)v.y; o[2] = (__bf16)v.z; o[3] = (__bf16)v.w;
    *reinterpret_cast<bf16x4*>(out + (size_t)i * 4) = o;
  }
}

// ---------------- merged weight converts (w_q,w_k,w_v -> w_qkv; w_o -> w_obf) ----------------
__global__ __launch_bounds__(256) void cvtw_kernel(const float* __restrict__ w_q,
                                                   const float* __restrict__ w_k,
                                                   const float* __restrict__ w_v,
                                                   const float* __restrict__ w_o,
                                                   __bf16* __restrict__ w_qkv,
                                                   __bf16* __restrict__ w_obf) {
  const int sel = blockIdx.y;
  const float* src = (sel == 0) ? w_q : (sel == 1) ? w_k : (sel == 2) ? w_v : w_o;
  __bf16* dst = (sel < 3) ? (w_qkv + (size_t)sel * DD * DD) : w_obf;
  int i = blockIdx.x * blockDim.x + threadIdx.x;
  float4 v = reinterpret_cast<const float4*>(src)[i];
  bf16x4 o;
  o[0] = (__bf16)v.x; o[1] = (__bf16)v.y; o[2] = (__bf16)v.z; o[3] = (__bf16)v.w;
  *reinterpret_cast<bf16x4*>(dst + (size_t)i * 4) = o;
}

// ---------------- phase-pipelined NT GEMM: C[M,N] = A[M,K] * B[N,K]^T ----------------
// BM=128, BN=256, BK=64. 8 waves (2M x 4N). Counted vmcnt(6), XOR-swizzled LDS, setprio.
// MODE 0: f32 out + bias. MODE 2: bf16 out; cols<DD scaled by 0.125*log2(e);
//         cols>=2*DD routed TRANSPOSED into vt[b,h,dk,s] (fused V-transpose).
template <int MODE>
__global__ __launch_bounds__(512, 1) void gemm8p(const unsigned short* __restrict__ A,
                                                 const unsigned short* __restrict__ Bm,
                                                 void* __restrict__ Cout,
                                                 const float* __restrict__ bias,
                                                 unsigned short* __restrict__ vt,
                                                 int Ndim, int K) {
  __shared__ __align__(16) unsigned short Asm[2 * 2 * 4096];   // [buf][kk][128*32]
  __shared__ __align__(16) unsigned short Bsm[2 * 2 * 8192];   // [buf][kk][256*32]
  const int tid = threadIdx.x, wid = tid >> 6, ln = tid & 63;
  const int wm = wid >> 2, wn = wid & 3;
  const int cl = ln & 15, ck = ln >> 4;

  // XCD-aware bijective swizzle (nwg % 8 == 0 for both launch configs)
  const int gx = gridDim.x;
  const int nwg = gx * gridDim.y;
  const int qch = nwg >> 3;
  int lid = blockIdx.y * gx + blockIdx.x;
  lid = (lid & 7) * qch + (lid >> 3);
  const int bn0 = (lid % gx) * 256;
  const int bm0 = (lid / gx) * 128;

  const int KT = K >> 6;
  const int sr = tid >> 2;                       // staging row 0..127
  const int scol = ((tid & 3) ^ (sr & 3)) << 3;  // pre-swizzled source col (shorts)
  const int sc8 = (ck ^ (cl & 3)) << 3;          // swizzled frag-read chunk (shorts)

  f32x4 acc[4][4] = {};

  auto stage_group = [&](int buf, int kt, int kk) {  // 3 loads: A-half + B-half(2)
    const int k0 = kt * 64 + kk * 32;
    const unsigned short* ga = A + (size_t)(bm0 + sr) * K + k0 + scol;
    __builtin_amdgcn_global_load_lds((GLOBAL_AS void*)ga,
        (LDS_AS void*)(Asm + (buf * 2 + kk) * 4096 + wid * 512), 16, 0, 0);
#pragma unroll
    for (int j = 0; j < 2; ++j) {
      const unsigned short* gb = Bm + (size_t)(bn0 + j * 128 + sr) * K + k0 + scol;
      __builtin_amdgcn_global_load_lds((GLOBAL_AS void*)gb,
          (LDS_AS void*)(Bsm + (buf * 2 + kk) * 8192 + j * 4096 + wid * 512), 16, 0, 0);
    }
  };

  auto phase = [&](int p, int kk, int g_buf, int g_kt, int g_kk, bool g_issue, int vm) {
    bf16x8 af[4], bfr[4];
    const unsigned short* ab = Asm + (p * 2 + kk) * 4096;
    const unsigned short* bb = Bsm + (p * 2 + kk) * 8192;
#pragma unroll
    for (int mf = 0; mf < 4; ++mf)
      af[mf] = *reinterpret_cast<const bf16x8*>(ab + (wm * 64 + mf * 16 + cl) * 32 + sc8);
#pragma unroll
    for (int nf = 0; nf < 4; ++nf)
      bfr[nf] = *reinterpret_cast<const bf16x8*>(bb + (wn * 64 + nf * 16 + cl) * 32 + sc8);
    if (g_issue) stage_group(g_buf, g_kt, g_kk);
    __builtin_amdgcn_s_barrier();
    __builtin_amdgcn_s_setprio(1);
#pragma unroll
    for (int mf = 0; mf < 4; ++mf)
#pragma unroll
      for (int nf = 0; nf < 4; ++nf)
        acc[mf][nf] = __builtin_amdgcn_mfma_f32_16x16x32_bf16(af[mf], bfr[nf], acc[mf][nf], 0, 0, 0);
    __builtin_amdgcn_s_setprio(0);
    if (vm == 6)      asm volatile("s_waitcnt vmcnt(6)" ::: "memory");
    else if (vm == 3) asm volatile("s_waitcnt vmcnt(3)" ::: "memory");
    else if (vm == 0) asm volatile("s_waitcnt vmcnt(0)" ::: "memory");
    __builtin_amdgcn_s_barrier();
  };

  // prologue
  stage_group(0, 0, 0);
  stage_group(0, 0, 1);
  stage_group(1, 1, 0);
  asm volatile("s_waitcnt vmcnt(6)" ::: "memory");
  __builtin_amdgcn_s_barrier();

  for (int kt = 0; kt < KT; ++kt) {
    const int p = kt & 1;
    const bool i0 = (kt + 1 < KT);
    const bool i1 = (kt + 2 < KT);
    phase(p, 0, p ^ 1, kt + 1, 1, i0, i0 ? 6 : 0);
    phase(p, 1, p, kt + 2, 0, i1, (kt < KT - 1) ? (i1 ? 6 : 3) : -1);
  }

  // epilogue
#pragma unroll
  for (int mf = 0; mf < 4; ++mf) {
#pragma unroll
    for (int nf = 0; nf < 4; ++nf) {
      const int col = bn0 + wn * 64 + nf * 16 + cl;
      if constexpr (MODE == 2) {
        if (col >= 2 * DD) {   // V part -> vt[b,h,dk,s], packed 8B
          const int hcol = col - 2 * DD;
          const int hh = hcol >> 6, dk = hcol & 63;
          const int row0 = bm0 + wm * 64 + mf * 16 + ck * 4;
          const int bb_ = row0 >> 11, s0 = row0 & 2047;
          bf16x4 pv;
#pragma unroll
          for (int r = 0; r < 4; ++r) pv[r] = (__bf16)acc[mf][nf][r];
          *reinterpret_cast<bf16x4*>(vt + ((size_t)((bb_ * HH + hh) * 64 + dk)) * SS + s0) = pv;
          continue;
        }
      }
#pragma unroll
      for (int r = 0; r < 4; ++r) {
        const int row = bm0 + wm * 64 + mf * 16 + ck * 4 + r;
        float v = acc[mf][nf][r];
        if constexpr (MODE == 0) {
          ((float*)Cout)[(size_t)row * Ndim + col] = v + bias[col];
        } else {
          if (col < DD) v *= 0.18033688011112042f;  // 0.125*log2(e)
          ((__bf16*)Cout)[(size_t)row * Ndim + col] = (__bf16)v;
        }
      }
    }
  }
}

// ---------------- causal flash attention (swapped-operand 32x32 MFMA, in-register P) ----------------
// grid (NQT/2, H, B); block i does q-tiles (NQT-1-i) then (i). 4 waves x 32 q-rows.
// QK^T computed as mfma(K,Q) -> each lane owns one q-row (col=lane&31), kv split across
// lane halves. Softmax fully in-register; P->bf16 via cvt_pk + permlane32_swap (T12).
// PV computed as mfma(V^T, P^T); row-sums via ones-MFMA. K/Vt double-buffered in LDS.
__global__ __launch_bounds__(256) void attn_kernel(const unsigned short* __restrict__ qkv,
                                                   const unsigned short* __restrict__ vt,
                                                   unsigned short* __restrict__ attn_out) {
  const int pi = blockIdx.x, h = blockIdx.y, b = blockIdx.z;
  const int tid = threadIdx.x, wv = tid >> 6, ln = tid & 63;
  const int l31 = ln & 31, hi = ln >> 5;
  const int bh = b * HH + h;

  __shared__ __align__(16) unsigned short Ks[2][64 * 64];
  __shared__ __align__(16) unsigned short Vs[2][64 * 64];

  bf16x8 vones;
#pragma unroll
  for (int j = 0; j < 8; ++j) vones[j] = (__bf16)1.0f;

  auto stage = [&](int bsel, int kv0s) {
#pragma unroll
    for (int i = 0; i < 2; ++i) {
      int idx = wv * 2 + i;
      int row = idx * 8 + (ln >> 3);
      int sch = (ln & 7) ^ (row & 7);   // pre-swizzled source chunk
      const unsigned short* gk = qkv + ((size_t)(b * SS + kv0s + row) * NQKV + DD + h * DKK + sch * 8);
      __builtin_amdgcn_global_load_lds((GLOBAL_AS void*)gk, (LDS_AS void*)(&Ks[bsel][idx * 512]), 16, 0, 0);
      const unsigned short* gv = vt + ((size_t)(bh * 64 + row) * SS + kv0s + sch * 8);
      __builtin_amdgcn_global_load_lds((GLOBAL_AS void*)gv, (LDS_AS void*)(&Vs[bsel][idx * 512]), 16, 0, 0);
    }
  };

  auto process = [&](int qt) {
    const int q0w = qt * 128 + wv * 32;
    const int qq = q0w + l31;          // this lane's q-row

    // Q B-fragments from global (L2-hot): qf[kkk] = Q[qq][kkk*16 + hi*8 .. +7]
    bf16x8 qf[4];
#pragma unroll
    for (int kkk = 0; kkk < 4; ++kkk)
      qf[kkk] = *reinterpret_cast<const bf16x8*>(
          qkv + (size_t)(b * SS + qq) * NQKV + h * DKK + kkk * 16 + hi * 8);

    f32x16 ot[2] = {};
    f32x16 lsum = {};
    float mrow = -INFINITY;

    const int nt = 2 * qt + 2;
    stage(0, 0);
    __syncthreads();
    int buf = 0;

    for (int t = 0; t < nt; ++t) {
      const int kv0 = t * 64;
      if (t + 1 < nt) stage(buf ^ 1, (t + 1) * 64);

      if (kv0 <= q0w + 31) {
        const unsigned short* kb = &Ks[buf][0];
        const unsigned short* vb = &Vs[buf][0];

        // ---- QK^T swapped: st[cc] = K-tile(cc) . Q^T ; C: col=q(l31), row=kv ----
        f32x16 st[2];
        __builtin_amdgcn_s_setprio(1);
#pragma unroll
        for (int cc = 0; cc < 2; ++cc) {
          f32x16 z = {};
#pragma unroll
          for (int kkk = 0; kkk < 4; ++kkk) {
            bf16x8 kf = *reinterpret_cast<const bf16x8*>(
                kb + (cc * 32 + l31) * 64 + (((kkk * 2 + hi) ^ (l31 & 7)) * 8));
            z = __builtin_amdgcn_mfma_f32_32x32x16_bf16(kf, qf[kkk], z, 0, 0, 0);
          }
          st[cc] = z;
        }
        __builtin_amdgcn_s_setprio(0);

        // ---- causal mask (diagonal tiles only): kv = kv0+32cc+4hi+(r&3)+8(r>>2) ----
        if (kv0 + 63 > q0w) {
          const int kvb = kv0 + 4 * hi;
#pragma unroll
          for (int cc = 0; cc < 2; ++cc)
#pragma unroll
            for (int r = 0; r < 16; ++r) {
              const int kv = kvb + cc * 32 + (r & 3) + 8 * (r >> 2);
              st[cc][r] = (kv <= qq) ? st[cc][r] : -INFINITY;
            }
        }

        // ---- row max (lane-local + one half-swap) ----
        float tm = st[0][0];
#pragma unroll
        for (int r = 1; r < 16; ++r) tm = fmaxf(tm, st[0][r]);
#pragma unroll
        for (int r = 0; r < 16; ++r) tm = fmaxf(tm, st[1][r]);
        tm = fmaxf(tm, __shfl_xor(tm, 32));

        // ---- defer-rescale (THR=8) ----
        if (__any(tm - mrow > 8.0f)) {
          float mn = fmaxf(mrow, tm);
          float al = __builtin_amdgcn_exp2f(mrow - mn);
          mrow = mn;
          lsum *= al;
          ot[0] *= al;
          ot[1] *= al;
        }

        // ---- P = exp2(S - m) (in-register) ----
#pragma unroll
        for (int cc = 0; cc < 2; ++cc)
#pragma unroll
          for (int r = 0; r < 16; ++r)
            st[cc][r] = __builtin_amdgcn_exp2f(st[cc][r] - mrow);

        // ---- pack to bf16 pairs: pk[g] = offsets {8g+4hi, +1}, pk2[g] = {8g+4hi+2, +3} ----
        unsigned int pk[2][4], pk2[2][4];
#pragma unroll
        for (int cc = 0; cc < 2; ++cc)
#pragma unroll
          for (int g = 0; g < 4; ++g) {
            pk[cc][g]  = cvt_pk_bf16(st[cc][4 * g + 0], st[cc][4 * g + 1]);
            pk2[cc][g] = cvt_pk_bf16(st[cc][4 * g + 2], st[cc][4 * g + 3]);
          }

        // ---- PV (swapped): ot[dc] += V^T(dc) . P^T ----
        // B-frag needs: hi=0 -> [own g0, own g0', partner g0, partner g0']
        //               hi=1 -> [partner g1, partner g1', own g1, own g1']
        // permlane32_swap(A,B) swaps A.hi <-> B.lo: A={own g0 | partner g1}, B={partner g0 | own g1}
        __builtin_amdgcn_s_setprio(1);
#pragma unroll
        for (int ks = 0; ks < 4; ++ks) {
          const int cc = ks >> 1, g0 = 2 * (ks & 1), g1 = g0 + 1;
          unsigned int Aw = pk[cc][g0], Bw = pk[cc][g1];
          asm volatile("v_permlane32_swap_b32 %0, %1" : "+v"(Aw), "+v"(Bw));
          unsigned int A2 = pk2[cc][g0], B2 = pk2[cc][g1];
          asm volatile("v_permlane32_swap_b32 %0, %1" : "+v"(A2), "+v"(B2));
          union { unsigned int u[4]; bf16x8 v; } pb;
          pb.u[0] = Aw; pb.u[1] = A2; pb.u[2] = Bw; pb.u[3] = B2;
          lsum = __builtin_amdgcn_mfma_f32_32x32x16_bf16(vones, pb.v, lsum, 0, 0, 0);
#pragma unroll
          for (int dc = 0; dc < 2; ++dc) {
            bf16x8 vf = *reinterpret_cast<const bf16x8*>(
                vb + (dc * 32 + l31) * 64 + (((ks * 2 + hi) ^ (l31 & 7)) * 8));
            ot[dc] = __builtin_amdgcn_mfma_f32_32x32x16_bf16(vf, pb.v, ot[dc], 0, 0, 0);
          }
        }
        __builtin_amdgcn_s_setprio(0);
      }

      __syncthreads();
      buf ^= 1;
    }

    // ---- epilogue: O^T regs -> attn[b,q,h*64+d], packed 8B (4 consecutive d) ----
    const float inv = 1.0f / lsum[0];
    __bf16* aout = (__bf16*)attn_out + (size_t)(b * SS + qq) * DD + h * DKK;
#pragma unroll
    for (int dc = 0; dc < 2; ++dc)
#pragma unroll
      for (int g = 0; g < 4; ++g) {
        uint2 pw;
        pw.x = cvt_pk_bf16(ot[dc][4 * g + 0] * inv, ot[dc][4 * g + 1] * inv);
        pw.y = cvt_pk_bf16(ot[dc][4 * g + 2] * inv, ot[dc][4 * g + 3] * inv);
        *reinterpret_cast<uint2*>(aout + dc * 32 + 4 * hi + 8 * g) = pw;
      }
  };

  process(NQT - 1 - pi);   // heavy tile first
  process(pi);             // then light tile
}

// ---------------- launch ----------------
extern "C" void kernel_launch(void* const* d_in, const int* in_sizes, int n_in,
                              void* d_out, int out_size, void* d_ws, size_t ws_size,
                              hipStream_t stream) {
  const float* x = (const float*)d_in[0];
  const float* w_q = (const float*)d_in[1];
  const float* w_k = (const float*)d_in[2];
  const float* w_v = (const float*)d_in[3];
  const float* w_o = (const float*)d_in[4];
  const float* b_o = (const float*)d_in[5];
  float* out = (float*)d_out;

  unsigned short* ws = (unsigned short*)d_ws;
  unsigned short* x_bf = ws;                               // 8192*1024
  unsigned short* w_qkv = x_bf + (size_t)MM * DD;          // 3072*1024
  unsigned short* w_obf = w_qkv + (size_t)NQKV * DD;       // 1024*1024
  unsigned short* qkv = w_obf + (size_t)DD * DD;           // 8192*3072 (V region unused)
  unsigned short* vt = qkv + (size_t)MM * NQKV;            // B*H*DK*S = 8388608
  unsigned short* attn = vt + (size_t)BB * HH * DKK * SS;  // 8192*1024

  // converts
  cvt_kernel<<<(MM * DD / 4 + 255) / 256, 256, 0, stream>>>(x, (__bf16*)x_bf, MM * DD / 4);
  cvtw_kernel<<<dim3(DD * DD / 4 / 256, 4), 256, 0, stream>>>(w_q, w_k, w_v, w_o,
                                                              (__bf16*)w_qkv, (__bf16*)w_obf);

  // QKV projection (Q prescaled; V written transposed into vt)
  gemm8p<2><<<dim3(NQKV / 256, MM / 128), 512, 0, stream>>>(x_bf, w_qkv, qkv, nullptr, vt, NQKV, DD);

  // attention (pair-balanced causal schedule)
  attn_kernel<<<dim3(NQT / 2, HH, BB), 256, 0, stream>>>(qkv, vt, attn);

  // output projection: [8192,1024] = attn @ w_o^T + b_o
  gemm8p<0><<<dim3(DD / 256, MM / 128), 512, 0, stream>>>(attn, w_obf, out, b_o, nullptr, DD, DD);
}